// Round 15
// baseline (514.594 us; speedup 1.0000x reference)
//
#include <hip/hip_runtime.h>
#include <stdint.h>

typedef __attribute__((ext_vector_type(8))) short bf16x8;
typedef __attribute__((ext_vector_type(4))) float f32x4;
typedef __attribute__((ext_vector_type(4))) uint32_t u32x4;
typedef unsigned short ushort;

#define XSS 392   // xs row stride (shorts)
#define HSS 144   // hs/gs row stride (shorts); swizzle mask = ((row>>2)&3)*40
#define TE 32

// ---------------- helpers ----------------
__device__ __forceinline__ float sigm(float x) { return __fdividef(1.0f, 1.0f + __expf(-x)); }
__device__ __forceinline__ float silu(float x) { return __fdividef(x, 1.0f + __expf(-x)); }
__device__ __forceinline__ short f2bf(float f) {  // RNE f32->bf16 (pack path)
  uint32_t u = __float_as_uint(f);
  u = (u + 0x7fffu + ((u >> 16) & 1u)) >> 16;
  return (short)u;
}
__device__ __forceinline__ uint32_t cvt2(float lo, float hi) {
  uint32_t d;
  asm("v_cvt_pk_bf16_f32 %0, %1, %2" : "=v"(d) : "v"(lo), "v"(hi));
  return d;
}
__device__ __forceinline__ short f2bf1(float f) { return (short)cvt2(f, f); }

__device__ __forceinline__ float jl_eval(int l, float x) {
  float s, c;
  sincosf(x, &s, &c);
  float ix = 1.0f / x, ix2 = ix * ix;
  if (l == 0) return s * ix;
  if (l == 1) return s * ix2 - c * ix;
  if (l == 2) return (3.0f * ix2 * ix - ix) * s - 3.0f * ix2 * c;
  return (15.0f * ix2 * ix2 - 6.0f * ix2) * s - (15.0f * ix2 * ix - ix) * c;
}

// ---------------- setup1: node_init + edge_geom + CSR counts ----------------
__global__ void setup1_kernel(const int* __restrict__ ntb, const float* __restrict__ emb,
                              float* __restrict__ nf, int N,
                              const float* __restrict__ pos, const int* __restrict__ src,
                              const int* __restrict__ dst, float* __restrict__ bvec,
                              float* __restrict__ bdist, float* __restrict__ rbf,
                              float* __restrict__ cut3, int E,
                              const int* __restrict__ t_src, int* __restrict__ cnt_e,
                              int* __restrict__ cnt_n, int T) {
  int i = blockIdx.x * 256 + threadIdx.x;
  if (i < N * 128) {
    int n = i >> 7, c = i & 127;
    nf[i] = emb[ntb[n] * 128 + c];
  }
  if (i < E) {
    int s = src[i], d = dst[i];
    float dx = pos[d * 3 + 0] - pos[s * 3 + 0];
    float dy = pos[d * 3 + 1] - pos[s * 3 + 1];
    float dz = pos[d * 3 + 2] - pos[s * 3 + 2];
    float r = sqrtf(dx * dx + dy * dy + dz * dz + 1e-12f);
    bvec[i * 3 + 0] = dx; bvec[i * 3 + 1] = dy; bvec[i * 3 + 2] = dz;
    bdist[i] = r;
    const float roots[3][3] = {
        {3.141592653589793f, 6.283185307179586f, 9.42477796076938f},
        {4.493409457909064f, 7.725251836937707f, 10.904121659428899f},
        {5.763459196894550f, 9.095011330476355f, 12.322940970566582f}};
#pragma unroll
    for (int l = 0; l < 3; ++l) {
#pragma unroll
      for (int n = 0; n < 3; ++n) {
        float root = roots[l][n];
        float x = r * (root * 0.2f);
        float norm;
        if (l == 0) norm = 1.0f / root;
        else if (l == 1) norm = 1.0f / sqrtf(1.0f + root * root);
        else {
          float t = 3.0f * root / (3.0f - root * root);
          norm = fabsf(t - root) / (root * root * sqrtf(1.0f + t * t));
        }
        rbf[i * 9 + l * 3 + n] = jl_eval(l, x) * (0.12649110640673518f / norm);
      }
    }
    float xx = r * 0.25f;
    float x3 = xx * xx * xx;
    cut3[i] = 1.0f - 6.0f * x3 * xx * xx + 15.0f * x3 * xx - 10.0f * x3;
    atomicAdd(&cnt_n[d], 1);
  }
  if (i < T) atomicAdd(&cnt_e[t_src[i]], 1);
}

// ---------------- setup2: block scans + atoms(k=0) (edge_emb fused into gmlp k=0) -------
__device__ void scan_chunk(const int* __restrict__ in, int* __restrict__ incl,
                           int* __restrict__ bsum, int L, int b) {
  __shared__ int sm[256];
  int i = b * 256 + threadIdx.x;
  int v = i < L ? in[i] : 0;
  sm[threadIdx.x] = v;
  __syncthreads();
  for (int st = 1; st < 256; st <<= 1) {
    int t = threadIdx.x >= st ? sm[threadIdx.x - st] : 0;
    __syncthreads();
    sm[threadIdx.x] += t;
    __syncthreads();
  }
  if (i < L) incl[i] = sm[threadIdx.x];
  if (threadIdx.x == 255) bsum[b] = sm[255];
}

__global__ void setup2_kernel(const int* __restrict__ cnt_e, int* __restrict__ incl_e,
                              int* __restrict__ bsum_e, int ebk, int E,
                              const int* __restrict__ cnt_n, int* __restrict__ incl_n,
                              int* __restrict__ bsum_n, int nbk, int N,
                              const float* __restrict__ nf, const float* __restrict__ taW,
                              const float* __restrict__ taB, float* __restrict__ atoms) {
  int b = blockIdx.x;
  if (b < ebk) scan_chunk(cnt_e, incl_e, bsum_e, E, b);
  else if (b < ebk + nbk) scan_chunk(cnt_n, incl_n, bsum_n, N, b - ebk);
  int i = b * 256 + threadIdx.x;
  if (i < N * 9) {
    int n = i / 9, d = i - n * 9;
    float acc = taB[d];
    for (int c = 0; c < 128; ++c) acc += nf[n * 128 + c] * taW[c * 9 + d];
    atoms[i] = sigm(acc);
  }
}

__global__ void scan_top2_kernel(int* __restrict__ bsum_e, int ne, int* __restrict__ bsum_n,
                                 int nn) {
  __shared__ int sm[1024];
  int* bs = blockIdx.x == 0 ? bsum_e : bsum_n;
  int nb = blockIdx.x == 0 ? ne : nn;
  int tid = threadIdx.x;
  int orig = tid < nb ? bs[tid] : 0;
  sm[tid] = orig;
  __syncthreads();
  for (int st = 1; st < 1024; st <<= 1) {
    int t = tid >= st ? sm[tid - st] : 0;
    __syncthreads();
    sm[tid] += t;
    __syncthreads();
  }
  if (tid < nb) bs[tid] = sm[tid] - orig;
}

__global__ void fin2_kernel(const int* __restrict__ cnt_e, const int* __restrict__ incl_e,
                            const int* __restrict__ bsum_e, int ebk, int* __restrict__ off_e,
                            int* __restrict__ cur_e, int E, const int* __restrict__ cnt_n,
                            const int* __restrict__ incl_n, const int* __restrict__ bsum_n,
                            int* __restrict__ off_n, int* __restrict__ cur_n, int N) {
  int b = blockIdx.x;
  if (b < ebk) {
    int i = b * 256 + threadIdx.x;
    if (i < E) {
      int o = incl_e[i] - cnt_e[i] + bsum_e[b];
      off_e[i] = o; cur_e[i] = o;
    }
  } else {
    int bb = b - ebk;
    int i = bb * 256 + threadIdx.x;
    if (i < N) {
      int o = incl_n[i] - cnt_n[i] + bsum_n[bb];
      off_n[i] = o; cur_n[i] = o;
    }
  }
}

// build: triplet precompute into CSR-sorted slots + inverse dst-permutation
__global__ void build_kernel(const int* __restrict__ t_src, const int* __restrict__ t_dst,
                             const int* __restrict__ dst, const float* __restrict__ bvec,
                             const float* __restrict__ bdist, const float* __restrict__ rbf,
                             const float* __restrict__ cut3, int* __restrict__ cur_e,
                             float* __restrict__ stbp, int* __restrict__ sa, int T,
                             int* __restrict__ cur_n, int* __restrict__ invp, int E) {
  int t = blockIdx.x * 256 + threadIdx.x;
  if (t < T) {
    int i = t_src[t], j = t_dst[t];
    float ax = bvec[i * 3], ay = bvec[i * 3 + 1], az = bvec[i * 3 + 2];
    float bx = bvec[j * 3], by = bvec[j * 3 + 1], bz = bvec[j * 3 + 2];
    float ct = (ax * bx + ay * by + az * bz) / (bdist[i] * bdist[j]);
    float tw = cut3[i] * cut3[j];
    float sh[3];
    sh[0] = 0.28209479177387814f * tw;
    sh[1] = 0.4886025119029199f * ct * tw;
    sh[2] = 0.31539156525252005f * (3.0f * ct * ct - 1.0f) * tw;
    int pos = atomicAdd(&cur_e[i], 1);
#pragma unroll
    for (int l = 0; l < 3; ++l)
#pragma unroll
      for (int n = 0; n < 3; ++n)
        stbp[(size_t)pos * 9 + l * 3 + n] = rbf[j * 9 + l * 3 + n] * sh[l];
    sa[pos] = dst[j];
  }
  if (t < E) {
    int pos = atomicAdd(&cur_n[dst[t]], 1);
    invp[t] = pos;
  }
}

// ---------------- weight packing (gmlp + tb + WT + eW, one launch) ----------------
__device__ void pack_one(const float* __restrict__ Wf, short* __restrict__ Wp, int K, int rr) {
  int per = 8 * (K / 32) * 64;
  int u = rr / per, r2 = rr - u * per;
  int lane = r2 & 63, tile = r2 >> 6;
  int kt = tile % (K / 32), nt = tile / (K / 32);
  int n = nt * 16 + (lane & 15);
  int k0 = kt * 32 + (lane >> 4) * 8;
  const float* s = Wf + (size_t)u * K * 128;
  bf16x8 v;
#pragma unroll
  for (int e = 0; e < 8; ++e) v[e] = f2bf(s[(size_t)(k0 + e) * 128 + n]);
  *(bf16x8*)(Wp + (size_t)u * K * 128 + (size_t)tile * 512 + lane * 8) = v;
}

__device__ void pack_pad9(const float* __restrict__ s, short* __restrict__ dp9, int l2) {
  int lane = l2 & 63, tile = l2 >> 6;
  int n = tile * 16 + (lane & 15);
  int k0 = (lane >> 4) * 8;
  bf16x8 v;
#pragma unroll
  for (int e = 0; e < 8; ++e)
    v[e] = (k0 + e < 9) ? f2bf(s[(size_t)(k0 + e) * 128 + n]) : (short)0;
  *(bf16x8*)(dp9 + tile * 512 + lane * 8) = v;
}

__global__ void pack_all_kernel(const float* __restrict__ W0, const float* __restrict__ G0,
                                const float* __restrict__ W1, const float* __restrict__ G1,
                                const float* __restrict__ W2, const float* __restrict__ G2,
                                const float* __restrict__ tbW, const float* __restrict__ tbG,
                                const float* __restrict__ WT, const float* __restrict__ eW,
                                short* __restrict__ pW0, short* __restrict__ pG0,
                                short* __restrict__ pW1, short* __restrict__ pG1,
                                short* __restrict__ pW2, short* __restrict__ pG2,
                                short* __restrict__ ptbW, short* __restrict__ ptbG,
                                short* __restrict__ pWT, short* __restrict__ peW) {
  int idx = blockIdx.x * 256 + threadIdx.x;
  const int t384 = 6 * 8 * 12 * 64, t128 = 6 * 8 * 4 * 64;
  if (idx < t384) { pack_one(W0, pW0, 384, idx); return; }
  if (idx < 2 * t384) { pack_one(G0, pG0, 384, idx - t384); return; }
  int j = idx - 2 * t384;
  if (j < t128) { pack_one(W1, pW1, 128, j); return; }
  if (j < 2 * t128) { pack_one(G1, pG1, 128, j - t128); return; }
  if (j < 3 * t128) { pack_one(W2, pW2, 128, j - 2 * t128); return; }
  if (j < 4 * t128) { pack_one(G2, pG2, 128, j - 3 * t128); return; }
  j -= 4 * t128;
  if (j < 3072) {  // tb weights: 3 k-blocks x {W,G} x 512
    int kb = j >> 10;
    int w2 = (j >> 9) & 1;
    int l2 = j & 511;
    const float* s = (w2 ? tbG : tbW) + (size_t)kb * 9 * 128;
    short* dp = (w2 ? ptbG : ptbW) + (size_t)kb * 4096;
    pack_pad9(s, dp, l2);
    return;
  }
  j -= 3072;
  if (j < 3072) {  // WT: 6 units x 512
    int u = j >> 9;
    pack_pad9(WT + (size_t)u * 9 * 128, pWT + (size_t)u * 4096, j & 511);
    return;
  }
  j -= 3072;
  if (j < 512) pack_pad9(eW, peW, j);  // edge-embedding weight
}

// ---------------- fused gated-MLP on MFMA ----------------
__device__ __forceinline__ f32x4 mfma16(bf16x8 a, bf16x8 b, f32x4 c) {
  return __builtin_amdgcn_mfma_f32_16x16x32_bf16(a, b, c, 0, 0, 0);
}

__device__ __forceinline__ void store_hg(short* hsb, short* gsb, int wave, int lane,
                                         const f32x4 (&aW)[2], const f32x4 (&aG)[2]) {
  const int lrow = lane & 15, lk = lane >> 4;
  const int colx = (wave * 16 + lrow) ^ (lk * 40);
#pragma unroll
  for (int mt = 0; mt < 2; ++mt)
#pragma unroll
    for (int rg = 0; rg < 4; ++rg) {
      int row = mt * 16 + lk * 4 + rg;
      hsb[row * HSS + colx] = f2bf1(silu(aW[mt][rg]));
      gsb[row * HSS + colx] = f2bf1(silu(aG[mt][rg]));
    }
}

__device__ __forceinline__ void layer128w(const short* hin, const short* gin,
                                          const short* __restrict__ pW,
                                          const short* __restrict__ pG,
                                          const float* __restrict__ Bh,
                                          const float* __restrict__ Bg, int wave, int lane,
                                          f32x4 (&aW)[2], f32x4 (&aG)[2]) {
  const int lrow = lane & 15, lk = lane >> 4;
  const int s0 = (lrow >> 2) & 3;
  float bw = Bh[wave * 16 + lrow], bg = Bg[wave * 16 + lrow];
  aW[0] = {bw, bw, bw, bw}; aW[1] = aW[0];
  aG[0] = {bg, bg, bg, bg}; aG[1] = aG[0];
#pragma unroll
  for (int kt = 0; kt < 4; ++kt) {
    int aoff = (kt * 32 + lk * 8) ^ (s0 * 40);
    bf16x8 ah0 = *(const bf16x8*)(hin + (size_t)lrow * HSS + aoff);
    bf16x8 ah1 = *(const bf16x8*)(hin + (size_t)(16 + lrow) * HSS + aoff);
    bf16x8 ag0 = *(const bf16x8*)(gin + (size_t)lrow * HSS + aoff);
    bf16x8 ag1 = *(const bf16x8*)(gin + (size_t)(16 + lrow) * HSS + aoff);
    bf16x8 bw8 = *(const bf16x8*)(pW + (size_t)(wave * 4 + kt) * 512 + lane * 8);
    bf16x8 bg8 = *(const bf16x8*)(pG + (size_t)(wave * 4 + kt) * 512 + lane * 8);
    aW[0] = mfma16(ah0, bw8, aW[0]);
    aW[1] = mfma16(ah1, bw8, aW[1]);
    aG[0] = mfma16(ag0, bg8, aG[0]);
    aG[1] = mfma16(ag1, bg8, aG[1]);
  }
}

__device__ __forceinline__ void run_chain(
    const short* xsb, short* hsb, short* gsb,
    const short* __restrict__ pW0, const short* __restrict__ pG0,
    const short* __restrict__ pW1, const short* __restrict__ pG1,
    const short* __restrict__ pW2, const short* __restrict__ pG2,
    const float* __restrict__ B0, const float* __restrict__ Gb0,
    const float* __restrict__ B1, const float* __restrict__ Gb1,
    const float* __restrict__ B2, const float* __restrict__ Gb2,
    int wave, int lane, f32x4 (&aW)[2], f32x4 (&aG)[2]) {
  const int lrow = lane & 15, lk = lane >> 4;
  const int s0 = (lrow >> 2) & 3;
  {
    float bw = B0[wave * 16 + lrow], bg = Gb0[wave * 16 + lrow];
    aW[0] = {bw, bw, bw, bw}; aW[1] = aW[0];
    aG[0] = {bg, bg, bg, bg}; aG[1] = aG[0];
  }
#pragma unroll
  for (int kt = 0; kt < 12; ++kt) {
    int al = kt * 32 + lk * 8;
    int aoff = (al < 256) ? al : (256 + ((al - 256) ^ (s0 << 4)));  // ef region swizzled
    bf16x8 a0 = *(const bf16x8*)(xsb + (size_t)lrow * XSS + aoff);
    bf16x8 a1 = *(const bf16x8*)(xsb + (size_t)(16 + lrow) * XSS + aoff);
    bf16x8 bw8 = *(const bf16x8*)(pW0 + (size_t)(wave * 12 + kt) * 512 + lane * 8);
    bf16x8 bg8 = *(const bf16x8*)(pG0 + (size_t)(wave * 12 + kt) * 512 + lane * 8);
    aW[0] = mfma16(a0, bw8, aW[0]);
    aW[1] = mfma16(a1, bw8, aW[1]);
    aG[0] = mfma16(a0, bg8, aG[0]);
    aG[1] = mfma16(a1, bg8, aG[1]);
  }
  store_hg(hsb, gsb, wave, lane, aW, aG);
  __syncthreads();
  layer128w(hsb, gsb, pW1, pG1, B1, Gb1, wave, lane, aW, aG);
  __syncthreads();
  store_hg(hsb, gsb, wave, lane, aW, aG);
  __syncthreads();
  layer128w(hsb, gsb, pW2, pG2, B2, Gb2, wave, lane, aW, aG);
}

__global__ __launch_bounds__(512, 6) void gmlp_fused(
    const float* __restrict__ nf, float* __restrict__ ef, const float* __restrict__ rbf,
    const int* __restrict__ src, const int* __restrict__ dst,
    const float* __restrict__ stbp, const int* __restrict__ sa,
    const int* __restrict__ off_e, const int* __restrict__ cnt_e,
    const float* __restrict__ atoms, const int* __restrict__ invp,
    const short* __restrict__ ptbW, const short* __restrict__ ptbG,
    const short* __restrict__ peW, const float* __restrict__ eB,
    const short* __restrict__ pW0a, const short* __restrict__ pG0a,
    const short* __restrict__ pW1a, const short* __restrict__ pG1a,
    const short* __restrict__ pW2a, const short* __restrict__ pG2a,
    const float* __restrict__ B0a, const float* __restrict__ Gb0a,
    const float* __restrict__ B1a, const float* __restrict__ Gb1a,
    const float* __restrict__ B2a, const float* __restrict__ Gb2a,
    const short* __restrict__ pWTa,
    const short* __restrict__ pW0b, const short* __restrict__ pG0b,
    const short* __restrict__ pW1b, const short* __restrict__ pG1b,
    const short* __restrict__ pW2b, const short* __restrict__ pG2b,
    const float* __restrict__ B0b, const float* __restrict__ Gb0b,
    const float* __restrict__ B1b, const float* __restrict__ Gb1b,
    const float* __restrict__ B2b, const float* __restrict__ Gb2b,
    const short* __restrict__ pWTb,
    float* __restrict__ mbuf, int E, int writeEf, int isK0) {
  __shared__ __align__(16) short xs[32][XSS];
  __shared__ __align__(16) short hs[32 * HSS];
  __shared__ __align__(16) short gs[32 * HSS];
  __shared__ __align__(16) short nbl[32][40];  // K=32-padded nb, bf16
  __shared__ __align__(16) short rbl[32][40];  // K=32-padded rbf, bf16
  __shared__ int invs[32];
  const int tid = threadIdx.x;
  const int e0 = blockIdx.x * TE;
  const int r = tid >> 4, q = tid & 15;
  int eg = e0 + r; if (eg >= E) eg = E - 1;

  // ---- fused nb_reduce -> bf16 nbl (zero-pad K 9..31) ----
  {
    float acc = 0.f;
    if (q < 9) {
      int o = off_e[eg], c = cnt_e[eg];
      for (int pp = o; pp < o + c; ++pp)
        acc += stbp[(size_t)pp * 9 + q] * atoms[(size_t)sa[pp] * 9 + q];
    }
    nbl[r][q] = (q < 9) ? f2bf1(acc) : (short)0;
    nbl[r][q + 16] = 0;
  }
  // ---- gather nf segments as bf16; rbf -> rbl bf16 ----
  {
    const float* sp0 = nf + (size_t)src[eg] * 128;
    const float* sp1 = nf + (size_t)dst[eg] * 128;
#pragma unroll
    for (int seg = 0; seg < 2; ++seg) {
      const float* sp = seg == 0 ? sp0 : sp1;
      float4 f0 = *(const float4*)(sp + q * 8);
      float4 f1 = *(const float4*)(sp + q * 8 + 4);
      u32x4 v = {cvt2(f0.x, f0.y), cvt2(f0.z, f0.w), cvt2(f1.x, f1.y), cvt2(f1.z, f1.w)};
      *(u32x4*)&xs[r][seg * 128 + q * 8] = v;
    }
    for (int idx = tid; idx < 32 * 32; idx += 512) {
      int rr = idx >> 5, d = idx & 31;
      int ee = e0 + rr; if (ee >= E) ee = E - 1;
      rbl[rr][d] = (d < 9) ? f2bf1(rbf[ee * 9 + d]) : (short)0;
    }
    if (tid < 32) {
      int ee = e0 + tid; if (ee >= E) ee = E - 1;
      invs[tid] = invp[ee];
    }
  }
  __syncthreads();

  const int wave = tid >> 6;
  const int lane = tid & 63;
  const int lrow = lane & 15, lk = lane >> 4;
  const int col = wave * 16 + lrow;
  const int cs = 256 + (col ^ (lk << 4));
  f32x4 aW[2], aG[2];
  float efb[2][4];  // ef + tb_update base, carried in registers through chain 0

  // ---- tb_update via MFMA (+ optional edge_emb at k=0) ----
  {
    bf16x8 ta0 = *(const bf16x8*)&nbl[lrow][lk * 8];
    bf16x8 ta1 = *(const bf16x8*)&nbl[16 + lrow][lk * 8];
    bf16x8 tbw = *(const bf16x8*)(ptbW + wave * 512 + lane * 8);
    bf16x8 tbg = *(const bf16x8*)(ptbG + wave * 512 + lane * 8);
    f32x4 z = {0.f, 0.f, 0.f, 0.f};
    f32x4 tW0 = mfma16(ta0, tbw, z), tW1 = mfma16(ta1, tbw, z);
    f32x4 tG0 = mfma16(ta0, tbg, z), tG1 = mfma16(ta1, tbg, z);
    f32x4 e0v = z, e1v = z;
    if (isK0) {  // ef = silu(rbf @ eW + eB), computed in-place
      bf16x8 ra0 = *(const bf16x8*)&rbl[lrow][lk * 8];
      bf16x8 ra1 = *(const bf16x8*)&rbl[16 + lrow][lk * 8];
      bf16x8 ew8 = *(const bf16x8*)(peW + wave * 512 + lane * 8);
      float ebv = eB[col];
      f32x4 ec = {ebv, ebv, ebv, ebv};
      e0v = mfma16(ra0, ew8, ec);
      e1v = mfma16(ra1, ew8, ec);
    }
#pragma unroll
    for (int mt = 0; mt < 2; ++mt)
#pragma unroll
      for (int rg = 0; rg < 4; ++rg) {
        int row = mt * 16 + lk * 4 + rg;
        int ec2 = e0 + row; if (ec2 >= E) ec2 = E - 1;
        float tw = mt == 0 ? tW0[rg] : tW1[rg];
        float tg = mt == 0 ? tG0[rg] : tG1[rg];
        float base_ef = isK0 ? silu(mt == 0 ? e0v[rg] : e1v[rg])
                             : ef[(size_t)ec2 * 128 + col];
        float base = base_ef + silu(tw) * sigm(tg);
        efb[mt][rg] = base;
        xs[row][cs] = f2bf1(base);
      }
  }
  __syncthreads();

  // ---- chain 0: edge update ----
  run_chain(&xs[0][0], hs, gs, pW0a, pG0a, pW1a, pG1a, pW2a, pG2a,
            B0a, Gb0a, B1a, Gb1a, B2a, Gb2a, wave, lane, aW, aG);
  {
    bf16x8 ra0 = *(const bf16x8*)&rbl[lrow][lk * 8];
    bf16x8 ra1 = *(const bf16x8*)&rbl[16 + lrow][lk * 8];
    bf16x8 wtb = *(const bf16x8*)(pWTa + wave * 512 + lane * 8);
    f32x4 z = {0.f, 0.f, 0.f, 0.f};
    f32x4 wv0 = mfma16(ra0, wtb, z), wv1 = mfma16(ra1, wtb, z);
#pragma unroll
    for (int mt = 0; mt < 2; ++mt)
#pragma unroll
      for (int rg = 0; rg < 4; ++rg) {
        int row = mt * 16 + lk * 4 + rg;
        int e = e0 + row;
        float wv = mt == 0 ? wv0[rg] : wv1[rg];
        float v = silu(aW[mt][rg]) * sigm(aG[mt][rg]) * wv;
        float nv = efb[mt][rg] + v;
        if (e < E && writeEf) ef[(size_t)e * 128 + col] = nv;
        xs[row][cs] = f2bf1(nv);
      }
  }
  __syncthreads();

  // ---- chain 1: node update ----
  run_chain(&xs[0][0], hs, gs, pW0b, pG0b, pW1b, pG1b, pW2b, pG2b,
            B0b, Gb0b, B1b, Gb1b, B2b, Gb2b, wave, lane, aW, aG);
  {
    bf16x8 ra0 = *(const bf16x8*)&rbl[lrow][lk * 8];
    bf16x8 ra1 = *(const bf16x8*)&rbl[16 + lrow][lk * 8];
    bf16x8 wtb = *(const bf16x8*)(pWTb + wave * 512 + lane * 8);
    f32x4 z = {0.f, 0.f, 0.f, 0.f};
    f32x4 wv0 = mfma16(ra0, wtb, z), wv1 = mfma16(ra1, wtb, z);
#pragma unroll
    for (int mt = 0; mt < 2; ++mt)
#pragma unroll
      for (int rg = 0; rg < 4; ++rg) {
        int row = mt * 16 + lk * 4 + rg;
        int e = e0 + row;
        float wv = mt == 0 ? wv0[rg] : wv1[rg];
        float v = silu(aW[mt][rg]) * sigm(aG[mt][rg]) * wv;
        if (e < E) mbuf[(size_t)invs[row] * 128 + col] = v;  // dst-sorted position
      }
  }
}

// ---- node gather (sequential, dst-sorted mbuf) + parallel fused atoms ----
__global__ void node_gather_kernel(float* __restrict__ nf, const float* __restrict__ mbuf,
                                   const int* __restrict__ off_n, const int* __restrict__ cnt_n,
                                   const float* __restrict__ taW, const float* __restrict__ taB,
                                   float* __restrict__ atoms, int N, int doAtoms) {
  __shared__ float red[2][9][128];
  int half = threadIdx.x >> 7, c = threadIdx.x & 127;
  int n = blockIdx.x * 2 + half;
  float v = 0.f;
  if (n < N) {
    int o = off_n[n], cnt = cnt_n[n];
    float acc = 0.f;
    for (int p = 0; p < cnt; ++p) acc += mbuf[(size_t)(o + p) * 128 + c];
    v = nf[(size_t)n * 128 + c] + acc;
    nf[(size_t)n * 128 + c] = v;
  }
  if (doAtoms) {
#pragma unroll
    for (int d = 0; d < 9; ++d) red[half][d][c] = (n < N) ? v * taW[c * 9 + d] : 0.f;
    for (int s = 64; s >= 1; s >>= 1) {
      __syncthreads();
      for (int idx = threadIdx.x; idx < 2 * 9 * s; idx += 256) {
        int h = idx / (9 * s), rem = idx - h * 9 * s;
        int d = rem / s, j = rem - d * s;
        red[h][d][j] += red[h][d][j + s];
      }
    }
    __syncthreads();
    if (threadIdx.x < 18) {
      int h = threadIdx.x / 9, d = threadIdx.x - h * 9;
      int nn = blockIdx.x * 2 + h;
      if (nn < N) atoms[nn * 9 + d] = sigm(red[h][d][0] + taB[d]);
    }
  }
}

// ---------------- readout ----------------
__global__ void mean_kernel(const float* __restrict__ nf, float* __restrict__ partial, int N) {
  __shared__ float sm[256];
  int n0 = blockIdx.x * 256;
  int col = threadIdx.x & 127, half = threadIdx.x >> 7;
  int nend = n0 + 256 < N ? n0 + 256 : N;
  float s = 0.f;
  for (int n = n0 + half; n < nend; n += 2) s += nf[n * 128 + col];
  sm[threadIdx.x] = s;
  __syncthreads();
  if (threadIdx.x < 128)
    partial[blockIdx.x * 128 + threadIdx.x] = sm[threadIdx.x] + sm[threadIdx.x + 128];
}

__global__ void final_kernel(const float* __restrict__ partial, int nchunks, float Nf,
                             const float* __restrict__ fW0, const float* __restrict__ fb0,
                             const float* __restrict__ fW1, const float* __restrict__ fb1,
                             const float* __restrict__ fW2, const float* __restrict__ fb2,
                             float* __restrict__ out) {
  __shared__ float v[128], h[128], red[128];
  int tid = threadIdx.x;  // 128 threads
  float s = 0.f;
  for (int b = 0; b < nchunks; ++b) s += partial[b * 128 + tid];
  v[tid] = s / Nf;
  __syncthreads();
  float acc = fb0[tid];
  for (int c = 0; c < 128; ++c) acc += v[c] * fW0[c * 128 + tid];
  h[tid] = silu(acc);
  __syncthreads();
  acc = fb1[tid];
  for (int c = 0; c < 128; ++c) acc += h[c] * fW1[c * 128 + tid];
  __syncthreads();
  v[tid] = silu(acc);
  __syncthreads();
  red[tid] = v[tid] * fW2[tid];
  __syncthreads();
  for (int st = 64; st > 0; st >>= 1) {
    if (tid < st) red[tid] += red[tid + st];
    __syncthreads();
  }
  if (tid == 0) out[0] = red[0] + fb2[0];
}

// ---------------- launch ----------------
extern "C" void kernel_launch(void* const* d_in, const int* in_sizes, int n_in,
                              void* d_out, int out_size, void* d_ws, size_t ws_size,
                              hipStream_t stream) {
  const float* pos = (const float*)d_in[0];
  const int* node_type = (const int*)d_in[1];
  const int* src = (const int*)d_in[2];
  const int* dst = (const int*)d_in[3];
  const int* t_src = (const int*)d_in[4];
  const int* t_dst = (const int*)d_in[5];
  const float* emb = (const float*)d_in[6];
  const float* eW = (const float*)d_in[7];
  const float* eB = (const float*)d_in[8];
  const float* taW = (const float*)d_in[9];
  const float* taB = (const float*)d_in[10];
  const float* tbW = (const float*)d_in[11];
  const float* tbG = (const float*)d_in[12];
  const float* W0 = (const float*)d_in[13]; const float* B0 = (const float*)d_in[14];
  const float* W1 = (const float*)d_in[15]; const float* B1 = (const float*)d_in[16];
  const float* W2 = (const float*)d_in[17]; const float* B2 = (const float*)d_in[18];
  const float* G0 = (const float*)d_in[19]; const float* Gb0 = (const float*)d_in[20];
  const float* G1 = (const float*)d_in[21]; const float* Gb1 = (const float*)d_in[22];
  const float* G2 = (const float*)d_in[23]; const float* Gb2 = (const float*)d_in[24];
  const float* WT = (const float*)d_in[25];
  const float* fW0 = (const float*)d_in[26]; const float* fb0 = (const float*)d_in[27];
  const float* fW1 = (const float*)d_in[28]; const float* fb1 = (const float*)d_in[29];
  const float* fW2 = (const float*)d_in[30]; const float* fb2 = (const float*)d_in[31];

  const int N = in_sizes[1];
  const int E = in_sizes[2];
  const int T = in_sizes[4];

  char* p = (char*)d_ws;
  auto alloc = [&](size_t bytes) -> char* {
    char* r = p;
    p += (bytes + 255) & ~(size_t)255;
    return r;
  };
  float*  nf    = (float*)alloc((size_t)N * 128 * 4);
  float*  ef    = (float*)alloc((size_t)E * 128 * 4);
  float*  mbuf  = (float*)alloc((size_t)E * 128 * 4);
  float*  rbf   = (float*)alloc((size_t)E * 9 * 4);
  float*  bvec  = (float*)alloc((size_t)E * 3 * 4);
  float*  bdist = (float*)alloc((size_t)E * 4);
  float*  cut3  = (float*)alloc((size_t)E * 4);
  float*  stbp  = (float*)alloc((size_t)T * 9 * 4);
  int*    sa    = (int*)alloc((size_t)T * 4);
  float*  atoms = (float*)alloc((size_t)N * 9 * 4);
  float*  part  = (float*)alloc((size_t)64 * 128 * 4);
  int* cnt_all = (int*)alloc((size_t)(E + N) * 4);
  int* cnt_e = cnt_all, *cnt_n = cnt_all + E;
  int* incl_e = (int*)alloc((size_t)E * 4);
  int* incl_n = (int*)alloc((size_t)N * 4);
  int* off_e  = (int*)alloc((size_t)E * 4);
  int* off_n  = (int*)alloc((size_t)N * 4);
  int* cur_e  = (int*)alloc((size_t)E * 4);
  int* cur_n  = (int*)alloc((size_t)N * 4);
  int* invp   = (int*)alloc((size_t)E * 4);
  int* bsum_e = (int*)alloc((size_t)1024 * 4);
  int* bsum_n = (int*)alloc((size_t)1024 * 4);
  short* pW0s = (short*)alloc((size_t)6 * 384 * 128 * 2);
  short* pG0s = (short*)alloc((size_t)6 * 384 * 128 * 2);
  short* pW1s = (short*)alloc((size_t)6 * 128 * 128 * 2);
  short* pG1s = (short*)alloc((size_t)6 * 128 * 128 * 2);
  short* pW2s = (short*)alloc((size_t)6 * 128 * 128 * 2);
  short* pG2s = (short*)alloc((size_t)6 * 128 * 128 * 2);
  short* ptbWs = (short*)alloc((size_t)3 * 4096 * 2);
  short* ptbGs = (short*)alloc((size_t)3 * 4096 * 2);
  short* pWTs  = (short*)alloc((size_t)6 * 4096 * 2);
  short* peWs  = (short*)alloc((size_t)4096 * 2);
  (void)ws_size; (void)n_in; (void)out_size;

  const int ebk = (E + 255) / 256, nbk = (N + 255) / 256;

  pack_all_kernel<<<506, 256, 0, stream>>>(W0, G0, W1, G1, W2, G2, tbW, tbG, WT, eW,
                                           pW0s, pG0s, pW1s, pG1s, pW2s, pG2s,
                                           ptbWs, ptbGs, pWTs, peWs);
  hipMemsetAsync(cnt_all, 0, (size_t)(E + N) * 4, stream);
  {
    int g1 = N * 128; if (E > g1) g1 = E; if (T > g1) g1 = T;
    setup1_kernel<<<(g1 + 255) / 256, 256, 0, stream>>>(
        node_type, emb, nf, N, pos, src, dst, bvec, bdist, rbf, cut3, E, t_src, cnt_e, cnt_n, T);
  }
  {
    int g2 = (ebk + nbk) * 256; if (N * 9 > g2) g2 = N * 9;
    setup2_kernel<<<(g2 + 255) / 256, 256, 0, stream>>>(
        cnt_e, incl_e, bsum_e, ebk, E, cnt_n, incl_n, bsum_n, nbk, N, nf, taW, taB, atoms);
  }
  scan_top2_kernel<<<2, 1024, 0, stream>>>(bsum_e, ebk, bsum_n, nbk);
  fin2_kernel<<<ebk + nbk, 256, 0, stream>>>(cnt_e, incl_e, bsum_e, ebk, off_e, cur_e, E,
                                             cnt_n, incl_n, bsum_n, off_n, cur_n, N);
  {
    int g3 = T > E ? T : E;
    build_kernel<<<(g3 + 255) / 256, 256, 0, stream>>>(t_src, t_dst, dst, bvec, bdist, rbf,
                                                       cut3, cur_e, stbp, sa, T, cur_n, invp, E);
  }

  const int gblocks = (E + TE - 1) / TE;
  for (int k = 0; k < 3; ++k) {
    size_t u0 = (size_t)(k * 2 + 0), u1 = u0 + 1;
    gmlp_fused<<<gblocks, 512, 0, stream>>>(
        nf, ef, rbf, src, dst, stbp, sa, off_e, cnt_e, atoms, invp,
        ptbWs + (size_t)k * 4096, ptbGs + (size_t)k * 4096, peWs, eB,
        pW0s + u0 * 384 * 128, pG0s + u0 * 384 * 128, pW1s + u0 * 128 * 128,
        pG1s + u0 * 128 * 128, pW2s + u0 * 128 * 128, pG2s + u0 * 128 * 128,
        B0 + u0 * 128, Gb0 + u0 * 128, B1 + u0 * 128, Gb1 + u0 * 128, B2 + u0 * 128,
        Gb2 + u0 * 128, pWTs + u0 * 4096,
        pW0s + u1 * 384 * 128, pG0s + u1 * 384 * 128, pW1s + u1 * 128 * 128,
        pG1s + u1 * 128 * 128, pW2s + u1 * 128 * 128, pG2s + u1 * 128 * 128,
        B0 + u1 * 128, Gb0 + u1 * 128, B1 + u1 * 128, Gb1 + u1 * 128, B2 + u1 * 128,
        Gb2 + u1 * 128, pWTs + u1 * 4096,
        mbuf, E, k < 2 ? 1 : 0, k == 0 ? 1 : 0);
    int nk = k < 2 ? k + 1 : 0;
    node_gather_kernel<<<(N + 1) / 2, 256, 0, stream>>>(
        nf, mbuf, off_n, cnt_n, taW + (size_t)nk * 128 * 9, taB + (size_t)nk * 9,
        atoms, N, k < 2 ? 1 : 0);
  }

  int nchunks = (N + 255) / 256;
  mean_kernel<<<nchunks, 256, 0, stream>>>(nf, part, N);
  final_kernel<<<1, 128, 0, stream>>>(part, nchunks, (float)N, fW0, fb0, fW1, fb1, fW2, fb2,
                                      (float*)d_out);
}

// Round 16
// 492.341 us; speedup vs baseline: 1.0452x; 1.0452x over previous
//
#include <hip/hip_runtime.h>
#include <stdint.h>

typedef __attribute__((ext_vector_type(8))) short bf16x8;
typedef __attribute__((ext_vector_type(4))) float f32x4;
typedef __attribute__((ext_vector_type(4))) uint32_t u32x4;
typedef unsigned short ushort;

#define XSS 392   // xs row stride (shorts)
#define HSS 144   // hs/gs row stride (shorts); swizzle mask = ((row>>2)&3)*40
#define TE 32

// ---------------- helpers ----------------
__device__ __forceinline__ float sigm(float x) { return __fdividef(1.0f, 1.0f + __expf(-x)); }
__device__ __forceinline__ float silu(float x) { return __fdividef(x, 1.0f + __expf(-x)); }
__device__ __forceinline__ short f2bf(float f) {  // RNE f32->bf16 (pack path)
  uint32_t u = __float_as_uint(f);
  u = (u + 0x7fffu + ((u >> 16) & 1u)) >> 16;
  return (short)u;
}
__device__ __forceinline__ uint32_t cvt2(float lo, float hi) {
  uint32_t d;
  asm("v_cvt_pk_bf16_f32 %0, %1, %2" : "=v"(d) : "v"(lo), "v"(hi));
  return d;
}
__device__ __forceinline__ short f2bf1(float f) { return (short)cvt2(f, f); }

__device__ __forceinline__ float jl_eval(int l, float x) {
  float s, c;
  sincosf(x, &s, &c);
  float ix = 1.0f / x, ix2 = ix * ix;
  if (l == 0) return s * ix;
  if (l == 1) return s * ix2 - c * ix;
  if (l == 2) return (3.0f * ix2 * ix - ix) * s - 3.0f * ix2 * c;
  return (15.0f * ix2 * ix2 - 6.0f * ix2) * s - (15.0f * ix2 * ix - ix) * c;
}

// ---------------- setup1: node_init + edge_geom + CSR counts ----------------
__global__ void setup1_kernel(const int* __restrict__ ntb, const float* __restrict__ emb,
                              float* __restrict__ nf, int N,
                              const float* __restrict__ pos, const int* __restrict__ src,
                              const int* __restrict__ dst, float* __restrict__ bvec,
                              float* __restrict__ bdist, float* __restrict__ rbf,
                              float* __restrict__ cut3, int E,
                              const int* __restrict__ t_src, int* __restrict__ cnt_e,
                              int* __restrict__ cnt_n, int T) {
  int i = blockIdx.x * 256 + threadIdx.x;
  if (i < N * 128) {
    int n = i >> 7, c = i & 127;
    nf[i] = emb[ntb[n] * 128 + c];
  }
  if (i < E) {
    int s = src[i], d = dst[i];
    float dx = pos[d * 3 + 0] - pos[s * 3 + 0];
    float dy = pos[d * 3 + 1] - pos[s * 3 + 1];
    float dz = pos[d * 3 + 2] - pos[s * 3 + 2];
    float r = sqrtf(dx * dx + dy * dy + dz * dz + 1e-12f);
    bvec[i * 3 + 0] = dx; bvec[i * 3 + 1] = dy; bvec[i * 3 + 2] = dz;
    bdist[i] = r;
    const float roots[3][3] = {
        {3.141592653589793f, 6.283185307179586f, 9.42477796076938f},
        {4.493409457909064f, 7.725251836937707f, 10.904121659428899f},
        {5.763459196894550f, 9.095011330476355f, 12.322940970566582f}};
#pragma unroll
    for (int l = 0; l < 3; ++l) {
#pragma unroll
      for (int n = 0; n < 3; ++n) {
        float root = roots[l][n];
        float x = r * (root * 0.2f);
        float norm;
        if (l == 0) norm = 1.0f / root;
        else if (l == 1) norm = 1.0f / sqrtf(1.0f + root * root);
        else {
          float t = 3.0f * root / (3.0f - root * root);
          norm = fabsf(t - root) / (root * root * sqrtf(1.0f + t * t));
        }
        rbf[i * 9 + l * 3 + n] = jl_eval(l, x) * (0.12649110640673518f / norm);
      }
    }
    float xx = r * 0.25f;
    float x3 = xx * xx * xx;
    cut3[i] = 1.0f - 6.0f * x3 * xx * xx + 15.0f * x3 * xx - 10.0f * x3;
    atomicAdd(&cnt_n[d], 1);
  }
  if (i < T) atomicAdd(&cnt_e[t_src[i]], 1);
}

// ---------------- setup2: block scans + atoms(k=0) (edge_emb fused into gmlp k=0) -------
__device__ void scan_chunk(const int* __restrict__ in, int* __restrict__ incl,
                           int* __restrict__ bsum, int L, int b) {
  __shared__ int sm[256];
  int i = b * 256 + threadIdx.x;
  int v = i < L ? in[i] : 0;
  sm[threadIdx.x] = v;
  __syncthreads();
  for (int st = 1; st < 256; st <<= 1) {
    int t = threadIdx.x >= st ? sm[threadIdx.x - st] : 0;
    __syncthreads();
    sm[threadIdx.x] += t;
    __syncthreads();
  }
  if (i < L) incl[i] = sm[threadIdx.x];
  if (threadIdx.x == 255) bsum[b] = sm[255];
}

__global__ void setup2_kernel(const int* __restrict__ cnt_e, int* __restrict__ incl_e,
                              int* __restrict__ bsum_e, int ebk, int E,
                              const int* __restrict__ cnt_n, int* __restrict__ incl_n,
                              int* __restrict__ bsum_n, int nbk, int N,
                              const float* __restrict__ nf, const float* __restrict__ taW,
                              const float* __restrict__ taB, float* __restrict__ atoms) {
  int b = blockIdx.x;
  if (b < ebk) scan_chunk(cnt_e, incl_e, bsum_e, E, b);
  else if (b < ebk + nbk) scan_chunk(cnt_n, incl_n, bsum_n, N, b - ebk);
  int i = b * 256 + threadIdx.x;
  if (i < N * 9) {
    int n = i / 9, d = i - n * 9;
    float acc = taB[d];
    for (int c = 0; c < 128; ++c) acc += nf[n * 128 + c] * taW[c * 9 + d];
    atoms[i] = sigm(acc);
  }
}

__global__ void scan_top2_kernel(int* __restrict__ bsum_e, int ne, int* __restrict__ bsum_n,
                                 int nn) {
  __shared__ int sm[1024];
  int* bs = blockIdx.x == 0 ? bsum_e : bsum_n;
  int nb = blockIdx.x == 0 ? ne : nn;
  int tid = threadIdx.x;
  int orig = tid < nb ? bs[tid] : 0;
  sm[tid] = orig;
  __syncthreads();
  for (int st = 1; st < 1024; st <<= 1) {
    int t = tid >= st ? sm[tid - st] : 0;
    __syncthreads();
    sm[tid] += t;
    __syncthreads();
  }
  if (tid < nb) bs[tid] = sm[tid] - orig;
}

__global__ void fin2_kernel(const int* __restrict__ cnt_e, const int* __restrict__ incl_e,
                            const int* __restrict__ bsum_e, int ebk, int* __restrict__ off_e,
                            int* __restrict__ cur_e, int E, const int* __restrict__ cnt_n,
                            const int* __restrict__ incl_n, const int* __restrict__ bsum_n,
                            int* __restrict__ off_n, int* __restrict__ cur_n, int N) {
  int b = blockIdx.x;
  if (b < ebk) {
    int i = b * 256 + threadIdx.x;
    if (i < E) {
      int o = incl_e[i] - cnt_e[i] + bsum_e[b];
      off_e[i] = o; cur_e[i] = o;
    }
  } else {
    int bb = b - ebk;
    int i = bb * 256 + threadIdx.x;
    if (i < N) {
      int o = incl_n[i] - cnt_n[i] + bsum_n[bb];
      off_n[i] = o; cur_n[i] = o;
    }
  }
}

// build: triplet precompute into CSR-sorted slots + inverse dst-permutation
__global__ void build_kernel(const int* __restrict__ t_src, const int* __restrict__ t_dst,
                             const int* __restrict__ dst, const float* __restrict__ bvec,
                             const float* __restrict__ bdist, const float* __restrict__ rbf,
                             const float* __restrict__ cut3, int* __restrict__ cur_e,
                             float* __restrict__ stbp, int* __restrict__ sa, int T,
                             int* __restrict__ cur_n, int* __restrict__ invp, int E) {
  int t = blockIdx.x * 256 + threadIdx.x;
  if (t < T) {
    int i = t_src[t], j = t_dst[t];
    float ax = bvec[i * 3], ay = bvec[i * 3 + 1], az = bvec[i * 3 + 2];
    float bx = bvec[j * 3], by = bvec[j * 3 + 1], bz = bvec[j * 3 + 2];
    float ct = (ax * bx + ay * by + az * bz) / (bdist[i] * bdist[j]);
    float tw = cut3[i] * cut3[j];
    float sh[3];
    sh[0] = 0.28209479177387814f * tw;
    sh[1] = 0.4886025119029199f * ct * tw;
    sh[2] = 0.31539156525252005f * (3.0f * ct * ct - 1.0f) * tw;
    int pos = atomicAdd(&cur_e[i], 1);
#pragma unroll
    for (int l = 0; l < 3; ++l)
#pragma unroll
      for (int n = 0; n < 3; ++n)
        stbp[(size_t)pos * 9 + l * 3 + n] = rbf[j * 9 + l * 3 + n] * sh[l];
    sa[pos] = dst[j];
  }
  if (t < E) {
    int pos = atomicAdd(&cur_n[dst[t]], 1);
    invp[t] = pos;
  }
}

// ---------------- weight packing (gmlp + tb + WT + eW, one launch) ----------------
__device__ void pack_one(const float* __restrict__ Wf, short* __restrict__ Wp, int K, int rr) {
  int per = 8 * (K / 32) * 64;
  int u = rr / per, r2 = rr - u * per;
  int lane = r2 & 63, tile = r2 >> 6;
  int kt = tile % (K / 32), nt = tile / (K / 32);
  int n = nt * 16 + (lane & 15);
  int k0 = kt * 32 + (lane >> 4) * 8;
  const float* s = Wf + (size_t)u * K * 128;
  bf16x8 v;
#pragma unroll
  for (int e = 0; e < 8; ++e) v[e] = f2bf(s[(size_t)(k0 + e) * 128 + n]);
  *(bf16x8*)(Wp + (size_t)u * K * 128 + (size_t)tile * 512 + lane * 8) = v;
}

__device__ void pack_pad9(const float* __restrict__ s, short* __restrict__ dp9, int l2) {
  int lane = l2 & 63, tile = l2 >> 6;
  int n = tile * 16 + (lane & 15);
  int k0 = (lane >> 4) * 8;
  bf16x8 v;
#pragma unroll
  for (int e = 0; e < 8; ++e)
    v[e] = (k0 + e < 9) ? f2bf(s[(size_t)(k0 + e) * 128 + n]) : (short)0;
  *(bf16x8*)(dp9 + tile * 512 + lane * 8) = v;
}

__global__ void pack_all_kernel(const float* __restrict__ W0, const float* __restrict__ G0,
                                const float* __restrict__ W1, const float* __restrict__ G1,
                                const float* __restrict__ W2, const float* __restrict__ G2,
                                const float* __restrict__ tbW, const float* __restrict__ tbG,
                                const float* __restrict__ WT, const float* __restrict__ eW,
                                short* __restrict__ pW0, short* __restrict__ pG0,
                                short* __restrict__ pW1, short* __restrict__ pG1,
                                short* __restrict__ pW2, short* __restrict__ pG2,
                                short* __restrict__ ptbW, short* __restrict__ ptbG,
                                short* __restrict__ pWT, short* __restrict__ peW) {
  int idx = blockIdx.x * 256 + threadIdx.x;
  const int t384 = 6 * 8 * 12 * 64, t128 = 6 * 8 * 4 * 64;
  if (idx < t384) { pack_one(W0, pW0, 384, idx); return; }
  if (idx < 2 * t384) { pack_one(G0, pG0, 384, idx - t384); return; }
  int j = idx - 2 * t384;
  if (j < t128) { pack_one(W1, pW1, 128, j); return; }
  if (j < 2 * t128) { pack_one(G1, pG1, 128, j - t128); return; }
  if (j < 3 * t128) { pack_one(W2, pW2, 128, j - 2 * t128); return; }
  if (j < 4 * t128) { pack_one(G2, pG2, 128, j - 3 * t128); return; }
  j -= 4 * t128;
  if (j < 3072) {  // tb weights: 3 k-blocks x {W,G} x 512
    int kb = j >> 10;
    int w2 = (j >> 9) & 1;
    int l2 = j & 511;
    const float* s = (w2 ? tbG : tbW) + (size_t)kb * 9 * 128;
    short* dp = (w2 ? ptbG : ptbW) + (size_t)kb * 4096;
    pack_pad9(s, dp, l2);
    return;
  }
  j -= 3072;
  if (j < 3072) {  // WT: 6 units x 512
    int u = j >> 9;
    pack_pad9(WT + (size_t)u * 9 * 128, pWT + (size_t)u * 4096, j & 511);
    return;
  }
  j -= 3072;
  if (j < 512) pack_pad9(eW, peW, j);  // edge-embedding weight
}

// ---------------- fused gated-MLP on MFMA ----------------
__device__ __forceinline__ f32x4 mfma16(bf16x8 a, bf16x8 b, f32x4 c) {
  return __builtin_amdgcn_mfma_f32_16x16x32_bf16(a, b, c, 0, 0, 0);
}

__device__ __forceinline__ void store_hg(short* hsb, short* gsb, int wave, int lane,
                                         const f32x4 (&aW)[2], const f32x4 (&aG)[2]) {
  const int lrow = lane & 15, lk = lane >> 4;
  const int colx = (wave * 16 + lrow) ^ (lk * 40);
#pragma unroll
  for (int mt = 0; mt < 2; ++mt)
#pragma unroll
    for (int rg = 0; rg < 4; ++rg) {
      int row = mt * 16 + lk * 4 + rg;
      hsb[row * HSS + colx] = f2bf1(silu(aW[mt][rg]));
      gsb[row * HSS + colx] = f2bf1(silu(aG[mt][rg]));
    }
}

__device__ __forceinline__ void layer128w(const short* hin, const short* gin,
                                          const short* __restrict__ pW,
                                          const short* __restrict__ pG,
                                          const float* __restrict__ Bh,
                                          const float* __restrict__ Bg, int wave, int lane,
                                          f32x4 (&aW)[2], f32x4 (&aG)[2]) {
  const int lrow = lane & 15, lk = lane >> 4;
  const int s0 = (lrow >> 2) & 3;
  float bw = Bh[wave * 16 + lrow], bg = Bg[wave * 16 + lrow];
  aW[0] = {bw, bw, bw, bw}; aW[1] = aW[0];
  aG[0] = {bg, bg, bg, bg}; aG[1] = aG[0];
#pragma unroll
  for (int kt = 0; kt < 4; ++kt) {
    int aoff = (kt * 32 + lk * 8) ^ (s0 * 40);
    bf16x8 ah0 = *(const bf16x8*)(hin + (size_t)lrow * HSS + aoff);
    bf16x8 ah1 = *(const bf16x8*)(hin + (size_t)(16 + lrow) * HSS + aoff);
    bf16x8 ag0 = *(const bf16x8*)(gin + (size_t)lrow * HSS + aoff);
    bf16x8 ag1 = *(const bf16x8*)(gin + (size_t)(16 + lrow) * HSS + aoff);
    bf16x8 bw8 = *(const bf16x8*)(pW + (size_t)(wave * 4 + kt) * 512 + lane * 8);
    bf16x8 bg8 = *(const bf16x8*)(pG + (size_t)(wave * 4 + kt) * 512 + lane * 8);
    aW[0] = mfma16(ah0, bw8, aW[0]);
    aW[1] = mfma16(ah1, bw8, aW[1]);
    aG[0] = mfma16(ag0, bg8, aG[0]);
    aG[1] = mfma16(ag1, bg8, aG[1]);
  }
}

__device__ __forceinline__ void run_chain(
    const short* xsb, short* hsb, short* gsb,
    const short* __restrict__ pW0, const short* __restrict__ pG0,
    const short* __restrict__ pW1, const short* __restrict__ pG1,
    const short* __restrict__ pW2, const short* __restrict__ pG2,
    const float* __restrict__ B0, const float* __restrict__ Gb0,
    const float* __restrict__ B1, const float* __restrict__ Gb1,
    const float* __restrict__ B2, const float* __restrict__ Gb2,
    int wave, int lane, f32x4 (&aW)[2], f32x4 (&aG)[2]) {
  const int lrow = lane & 15, lk = lane >> 4;
  const int s0 = (lrow >> 2) & 3;
  {
    float bw = B0[wave * 16 + lrow], bg = Gb0[wave * 16 + lrow];
    aW[0] = {bw, bw, bw, bw}; aW[1] = aW[0];
    aG[0] = {bg, bg, bg, bg}; aG[1] = aG[0];
  }
#pragma unroll
  for (int kt = 0; kt < 12; ++kt) {
    int al = kt * 32 + lk * 8;
    int aoff = (al < 256) ? al : (256 + ((al - 256) ^ (s0 << 4)));  // ef region swizzled
    bf16x8 a0 = *(const bf16x8*)(xsb + (size_t)lrow * XSS + aoff);
    bf16x8 a1 = *(const bf16x8*)(xsb + (size_t)(16 + lrow) * XSS + aoff);
    bf16x8 bw8 = *(const bf16x8*)(pW0 + (size_t)(wave * 12 + kt) * 512 + lane * 8);
    bf16x8 bg8 = *(const bf16x8*)(pG0 + (size_t)(wave * 12 + kt) * 512 + lane * 8);
    aW[0] = mfma16(a0, bw8, aW[0]);
    aW[1] = mfma16(a1, bw8, aW[1]);
    aG[0] = mfma16(a0, bg8, aG[0]);
    aG[1] = mfma16(a1, bg8, aG[1]);
  }
  store_hg(hsb, gsb, wave, lane, aW, aG);
  __syncthreads();
  layer128w(hsb, gsb, pW1, pG1, B1, Gb1, wave, lane, aW, aG);
  __syncthreads();
  store_hg(hsb, gsb, wave, lane, aW, aG);
  __syncthreads();
  layer128w(hsb, gsb, pW2, pG2, B2, Gb2, wave, lane, aW, aG);
}

template <int ISK0>
__global__ __launch_bounds__(512, 6) void gmlp_fused(
    const float* __restrict__ nf, float* __restrict__ ef, const float* __restrict__ rbf,
    const int* __restrict__ src, const int* __restrict__ dst,
    const float* __restrict__ stbp, const int* __restrict__ sa,
    const int* __restrict__ off_e, const int* __restrict__ cnt_e,
    const float* __restrict__ atoms, const int* __restrict__ invp,
    const short* __restrict__ ptbW, const short* __restrict__ ptbG,
    const short* __restrict__ peW, const float* __restrict__ eB,
    const short* __restrict__ pW0a, const short* __restrict__ pG0a,
    const short* __restrict__ pW1a, const short* __restrict__ pG1a,
    const short* __restrict__ pW2a, const short* __restrict__ pG2a,
    const float* __restrict__ B0a, const float* __restrict__ Gb0a,
    const float* __restrict__ B1a, const float* __restrict__ Gb1a,
    const float* __restrict__ B2a, const float* __restrict__ Gb2a,
    const short* __restrict__ pWTa,
    const short* __restrict__ pW0b, const short* __restrict__ pG0b,
    const short* __restrict__ pW1b, const short* __restrict__ pG1b,
    const short* __restrict__ pW2b, const short* __restrict__ pG2b,
    const float* __restrict__ B0b, const float* __restrict__ Gb0b,
    const float* __restrict__ B1b, const float* __restrict__ Gb1b,
    const float* __restrict__ B2b, const float* __restrict__ Gb2b,
    const short* __restrict__ pWTb,
    float* __restrict__ mbuf, int E, int writeEf) {
  __shared__ __align__(16) short xs[32][XSS];
  __shared__ __align__(16) short hs[32 * HSS];
  __shared__ __align__(16) short gs[32 * HSS];
  __shared__ __align__(16) short nbl[32][40];  // K=32-padded nb, bf16
  __shared__ __align__(16) short rbl[32][40];  // K=32-padded rbf, bf16
  __shared__ int invs[32];
  const int tid = threadIdx.x;
  const int e0 = blockIdx.x * TE;
  const int r = tid >> 4, q = tid & 15;
  int eg = e0 + r; if (eg >= E) eg = E - 1;

  // ---- fused nb_reduce -> bf16 nbl (zero-pad K 9..31) ----
  {
    float acc = 0.f;
    if (q < 9) {
      int o = off_e[eg], c = cnt_e[eg];
      for (int pp = o; pp < o + c; ++pp)
        acc += stbp[(size_t)pp * 9 + q] * atoms[(size_t)sa[pp] * 9 + q];
    }
    nbl[r][q] = (q < 9) ? f2bf1(acc) : (short)0;
    nbl[r][q + 16] = 0;
  }
  // ---- gather nf segments as bf16; rbf -> rbl bf16 ----
  {
    const float* sp0 = nf + (size_t)src[eg] * 128;
    const float* sp1 = nf + (size_t)dst[eg] * 128;
#pragma unroll
    for (int seg = 0; seg < 2; ++seg) {
      const float* sp = seg == 0 ? sp0 : sp1;
      float4 f0 = *(const float4*)(sp + q * 8);
      float4 f1 = *(const float4*)(sp + q * 8 + 4);
      u32x4 v = {cvt2(f0.x, f0.y), cvt2(f0.z, f0.w), cvt2(f1.x, f1.y), cvt2(f1.z, f1.w)};
      *(u32x4*)&xs[r][seg * 128 + q * 8] = v;
    }
    for (int idx = tid; idx < 32 * 32; idx += 512) {
      int rr = idx >> 5, d = idx & 31;
      int ee = e0 + rr; if (ee >= E) ee = E - 1;
      rbl[rr][d] = (d < 9) ? f2bf1(rbf[ee * 9 + d]) : (short)0;
    }
    if (tid < 32) {
      int ee = e0 + tid; if (ee >= E) ee = E - 1;
      invs[tid] = invp[ee];
    }
  }
  __syncthreads();

  const int wave = tid >> 6;
  const int lane = tid & 63;
  const int lrow = lane & 15, lk = lane >> 4;
  const int col = wave * 16 + lrow;
  const int cs = 256 + (col ^ (lk << 4));
  f32x4 aW[2], aG[2];
  float efb[2][4];  // ef + tb_update base, carried in registers through chain 0

  // ---- tb_update via MFMA (+ compile-time edge_emb fusion at k=0) ----
  {
    bf16x8 ta0 = *(const bf16x8*)&nbl[lrow][lk * 8];
    bf16x8 ta1 = *(const bf16x8*)&nbl[16 + lrow][lk * 8];
    bf16x8 tbw = *(const bf16x8*)(ptbW + wave * 512 + lane * 8);
    bf16x8 tbg = *(const bf16x8*)(ptbG + wave * 512 + lane * 8);
    f32x4 z = {0.f, 0.f, 0.f, 0.f};
    f32x4 tW0 = mfma16(ta0, tbw, z), tW1 = mfma16(ta1, tbw, z);
    f32x4 tG0 = mfma16(ta0, tbg, z), tG1 = mfma16(ta1, tbg, z);
    if (ISK0) {  // ef = silu(rbf @ eW + eB), computed in-place
      bf16x8 ra0 = *(const bf16x8*)&rbl[lrow][lk * 8];
      bf16x8 ra1 = *(const bf16x8*)&rbl[16 + lrow][lk * 8];
      bf16x8 ew8 = *(const bf16x8*)(peW + wave * 512 + lane * 8);
      float ebv = eB[col];
      f32x4 ec = {ebv, ebv, ebv, ebv};
      f32x4 e0v = mfma16(ra0, ew8, ec);
      f32x4 e1v = mfma16(ra1, ew8, ec);
#pragma unroll
      for (int mt = 0; mt < 2; ++mt)
#pragma unroll
        for (int rg = 0; rg < 4; ++rg) {
          int row = mt * 16 + lk * 4 + rg;
          float tw = mt == 0 ? tW0[rg] : tW1[rg];
          float tg = mt == 0 ? tG0[rg] : tG1[rg];
          float base = silu(mt == 0 ? e0v[rg] : e1v[rg]) + silu(tw) * sigm(tg);
          efb[mt][rg] = base;
          xs[row][cs] = f2bf1(base);
        }
    } else {
#pragma unroll
      for (int mt = 0; mt < 2; ++mt)
#pragma unroll
        for (int rg = 0; rg < 4; ++rg) {
          int row = mt * 16 + lk * 4 + rg;
          int ec2 = e0 + row; if (ec2 >= E) ec2 = E - 1;
          float tw = mt == 0 ? tW0[rg] : tW1[rg];
          float tg = mt == 0 ? tG0[rg] : tG1[rg];
          float base = ef[(size_t)ec2 * 128 + col] + silu(tw) * sigm(tg);
          efb[mt][rg] = base;
          xs[row][cs] = f2bf1(base);
        }
    }
  }
  __syncthreads();

  // ---- chain 0: edge update ----
  run_chain(&xs[0][0], hs, gs, pW0a, pG0a, pW1a, pG1a, pW2a, pG2a,
            B0a, Gb0a, B1a, Gb1a, B2a, Gb2a, wave, lane, aW, aG);
  {
    bf16x8 ra0 = *(const bf16x8*)&rbl[lrow][lk * 8];
    bf16x8 ra1 = *(const bf16x8*)&rbl[16 + lrow][lk * 8];
    bf16x8 wtb = *(const bf16x8*)(pWTa + wave * 512 + lane * 8);
    f32x4 z = {0.f, 0.f, 0.f, 0.f};
    f32x4 wv0 = mfma16(ra0, wtb, z), wv1 = mfma16(ra1, wtb, z);
#pragma unroll
    for (int mt = 0; mt < 2; ++mt)
#pragma unroll
      for (int rg = 0; rg < 4; ++rg) {
        int row = mt * 16 + lk * 4 + rg;
        int e = e0 + row;
        float wv = mt == 0 ? wv0[rg] : wv1[rg];
        float v = silu(aW[mt][rg]) * sigm(aG[mt][rg]) * wv;
        float nv = efb[mt][rg] + v;
        if (e < E && writeEf) ef[(size_t)e * 128 + col] = nv;
        xs[row][cs] = f2bf1(nv);
      }
  }
  __syncthreads();

  // ---- chain 1: node update ----
  run_chain(&xs[0][0], hs, gs, pW0b, pG0b, pW1b, pG1b, pW2b, pG2b,
            B0b, Gb0b, B1b, Gb1b, B2b, Gb2b, wave, lane, aW, aG);
  {
    bf16x8 ra0 = *(const bf16x8*)&rbl[lrow][lk * 8];
    bf16x8 ra1 = *(const bf16x8*)&rbl[16 + lrow][lk * 8];
    bf16x8 wtb = *(const bf16x8*)(pWTb + wave * 512 + lane * 8);
    f32x4 z = {0.f, 0.f, 0.f, 0.f};
    f32x4 wv0 = mfma16(ra0, wtb, z), wv1 = mfma16(ra1, wtb, z);
#pragma unroll
    for (int mt = 0; mt < 2; ++mt)
#pragma unroll
      for (int rg = 0; rg < 4; ++rg) {
        int row = mt * 16 + lk * 4 + rg;
        int e = e0 + row;
        float wv = mt == 0 ? wv0[rg] : wv1[rg];
        float v = silu(aW[mt][rg]) * sigm(aG[mt][rg]) * wv;
        if (e < E) mbuf[(size_t)invs[row] * 128 + col] = v;  // dst-sorted position
      }
  }
}

// ---- node gather (sequential, dst-sorted mbuf) + parallel fused atoms ----
__global__ void node_gather_kernel(float* __restrict__ nf, const float* __restrict__ mbuf,
                                   const int* __restrict__ off_n, const int* __restrict__ cnt_n,
                                   const float* __restrict__ taW, const float* __restrict__ taB,
                                   float* __restrict__ atoms, int N, int doAtoms) {
  __shared__ float red[2][9][128];
  int half = threadIdx.x >> 7, c = threadIdx.x & 127;
  int n = blockIdx.x * 2 + half;
  float v = 0.f;
  if (n < N) {
    int o = off_n[n], cnt = cnt_n[n];
    float acc = 0.f;
    for (int p = 0; p < cnt; ++p) acc += mbuf[(size_t)(o + p) * 128 + c];
    v = nf[(size_t)n * 128 + c] + acc;
    nf[(size_t)n * 128 + c] = v;
  }
  if (doAtoms) {
#pragma unroll
    for (int d = 0; d < 9; ++d) red[half][d][c] = (n < N) ? v * taW[c * 9 + d] : 0.f;
    for (int s = 64; s >= 1; s >>= 1) {
      __syncthreads();
      for (int idx = threadIdx.x; idx < 2 * 9 * s; idx += 256) {
        int h = idx / (9 * s), rem = idx - h * 9 * s;
        int d = rem / s, j = rem - d * s;
        red[h][d][j] += red[h][d][j + s];
      }
    }
    __syncthreads();
    if (threadIdx.x < 18) {
      int h = threadIdx.x / 9, d = threadIdx.x - h * 9;
      int nn = blockIdx.x * 2 + h;
      if (nn < N) atoms[nn * 9 + d] = sigm(red[h][d][0] + taB[d]);
    }
  }
}

// ---------------- readout ----------------
__global__ void mean_kernel(const float* __restrict__ nf, float* __restrict__ partial, int N) {
  __shared__ float sm[256];
  int n0 = blockIdx.x * 256;
  int col = threadIdx.x & 127, half = threadIdx.x >> 7;
  int nend = n0 + 256 < N ? n0 + 256 : N;
  float s = 0.f;
  for (int n = n0 + half; n < nend; n += 2) s += nf[n * 128 + col];
  sm[threadIdx.x] = s;
  __syncthreads();
  if (threadIdx.x < 128)
    partial[blockIdx.x * 128 + threadIdx.x] = sm[threadIdx.x] + sm[threadIdx.x + 128];
}

__global__ void final_kernel(const float* __restrict__ partial, int nchunks, float Nf,
                             const float* __restrict__ fW0, const float* __restrict__ fb0,
                             const float* __restrict__ fW1, const float* __restrict__ fb1,
                             const float* __restrict__ fW2, const float* __restrict__ fb2,
                             float* __restrict__ out) {
  __shared__ float v[128], h[128], red[128];
  int tid = threadIdx.x;  // 128 threads
  float s = 0.f;
  for (int b = 0; b < nchunks; ++b) s += partial[b * 128 + tid];
  v[tid] = s / Nf;
  __syncthreads();
  float acc = fb0[tid];
  for (int c = 0; c < 128; ++c) acc += v[c] * fW0[c * 128 + tid];
  h[tid] = silu(acc);
  __syncthreads();
  acc = fb1[tid];
  for (int c = 0; c < 128; ++c) acc += h[c] * fW1[c * 128 + tid];
  __syncthreads();
  v[tid] = silu(acc);
  __syncthreads();
  red[tid] = v[tid] * fW2[tid];
  __syncthreads();
  for (int st = 64; st > 0; st >>= 1) {
    if (tid < st) red[tid] += red[tid + st];
    __syncthreads();
  }
  if (tid == 0) out[0] = red[0] + fb2[0];
}

// ---------------- launch ----------------
extern "C" void kernel_launch(void* const* d_in, const int* in_sizes, int n_in,
                              void* d_out, int out_size, void* d_ws, size_t ws_size,
                              hipStream_t stream) {
  const float* pos = (const float*)d_in[0];
  const int* node_type = (const int*)d_in[1];
  const int* src = (const int*)d_in[2];
  const int* dst = (const int*)d_in[3];
  const int* t_src = (const int*)d_in[4];
  const int* t_dst = (const int*)d_in[5];
  const float* emb = (const float*)d_in[6];
  const float* eW = (const float*)d_in[7];
  const float* eB = (const float*)d_in[8];
  const float* taW = (const float*)d_in[9];
  const float* taB = (const float*)d_in[10];
  const float* tbW = (const float*)d_in[11];
  const float* tbG = (const float*)d_in[12];
  const float* W0 = (const float*)d_in[13]; const float* B0 = (const float*)d_in[14];
  const float* W1 = (const float*)d_in[15]; const float* B1 = (const float*)d_in[16];
  const float* W2 = (const float*)d_in[17]; const float* B2 = (const float*)d_in[18];
  const float* G0 = (const float*)d_in[19]; const float* Gb0 = (const float*)d_in[20];
  const float* G1 = (const float*)d_in[21]; const float* Gb1 = (const float*)d_in[22];
  const float* G2 = (const float*)d_in[23]; const float* Gb2 = (const float*)d_in[24];
  const float* WT = (const float*)d_in[25];
  const float* fW0 = (const float*)d_in[26]; const float* fb0 = (const float*)d_in[27];
  const float* fW1 = (const float*)d_in[28]; const float* fb1 = (const float*)d_in[29];
  const float* fW2 = (const float*)d_in[30]; const float* fb2 = (const float*)d_in[31];

  const int N = in_sizes[1];
  const int E = in_sizes[2];
  const int T = in_sizes[4];

  char* p = (char*)d_ws;
  auto alloc = [&](size_t bytes) -> char* {
    char* r = p;
    p += (bytes + 255) & ~(size_t)255;
    return r;
  };
  float*  nf    = (float*)alloc((size_t)N * 128 * 4);
  float*  ef    = (float*)alloc((size_t)E * 128 * 4);
  float*  mbuf  = (float*)alloc((size_t)E * 128 * 4);
  float*  rbf   = (float*)alloc((size_t)E * 9 * 4);
  float*  bvec  = (float*)alloc((size_t)E * 3 * 4);
  float*  bdist = (float*)alloc((size_t)E * 4);
  float*  cut3  = (float*)alloc((size_t)E * 4);
  float*  stbp  = (float*)alloc((size_t)T * 9 * 4);
  int*    sa    = (int*)alloc((size_t)T * 4);
  float*  atoms = (float*)alloc((size_t)N * 9 * 4);
  float*  part  = (float*)alloc((size_t)64 * 128 * 4);
  int* cnt_all = (int*)alloc((size_t)(E + N) * 4);
  int* cnt_e = cnt_all, *cnt_n = cnt_all + E;
  int* incl_e = (int*)alloc((size_t)E * 4);
  int* incl_n = (int*)alloc((size_t)N * 4);
  int* off_e  = (int*)alloc((size_t)E * 4);
  int* off_n  = (int*)alloc((size_t)N * 4);
  int* cur_e  = (int*)alloc((size_t)E * 4);
  int* cur_n  = (int*)alloc((size_t)N * 4);
  int* invp   = (int*)alloc((size_t)E * 4);
  int* bsum_e = (int*)alloc((size_t)1024 * 4);
  int* bsum_n = (int*)alloc((size_t)1024 * 4);
  short* pW0s = (short*)alloc((size_t)6 * 384 * 128 * 2);
  short* pG0s = (short*)alloc((size_t)6 * 384 * 128 * 2);
  short* pW1s = (short*)alloc((size_t)6 * 128 * 128 * 2);
  short* pG1s = (short*)alloc((size_t)6 * 128 * 128 * 2);
  short* pW2s = (short*)alloc((size_t)6 * 128 * 128 * 2);
  short* pG2s = (short*)alloc((size_t)6 * 128 * 128 * 2);
  short* ptbWs = (short*)alloc((size_t)3 * 4096 * 2);
  short* ptbGs = (short*)alloc((size_t)3 * 4096 * 2);
  short* pWTs  = (short*)alloc((size_t)6 * 4096 * 2);
  short* peWs  = (short*)alloc((size_t)4096 * 2);
  (void)ws_size; (void)n_in; (void)out_size;

  const int ebk = (E + 255) / 256, nbk = (N + 255) / 256;

  pack_all_kernel<<<506, 256, 0, stream>>>(W0, G0, W1, G1, W2, G2, tbW, tbG, WT, eW,
                                           pW0s, pG0s, pW1s, pG1s, pW2s, pG2s,
                                           ptbWs, ptbGs, pWTs, peWs);
  hipMemsetAsync(cnt_all, 0, (size_t)(E + N) * 4, stream);
  {
    int g1 = N * 128; if (E > g1) g1 = E; if (T > g1) g1 = T;
    setup1_kernel<<<(g1 + 255) / 256, 256, 0, stream>>>(
        node_type, emb, nf, N, pos, src, dst, bvec, bdist, rbf, cut3, E, t_src, cnt_e, cnt_n, T);
  }
  {
    int g2 = (ebk + nbk) * 256; if (N * 9 > g2) g2 = N * 9;
    setup2_kernel<<<(g2 + 255) / 256, 256, 0, stream>>>(
        cnt_e, incl_e, bsum_e, ebk, E, cnt_n, incl_n, bsum_n, nbk, N, nf, taW, taB, atoms);
  }
  scan_top2_kernel<<<2, 1024, 0, stream>>>(bsum_e, ebk, bsum_n, nbk);
  fin2_kernel<<<ebk + nbk, 256, 0, stream>>>(cnt_e, incl_e, bsum_e, ebk, off_e, cur_e, E,
                                             cnt_n, incl_n, bsum_n, off_n, cur_n, N);
  {
    int g3 = T > E ? T : E;
    build_kernel<<<(g3 + 255) / 256, 256, 0, stream>>>(t_src, t_dst, dst, bvec, bdist, rbf,
                                                       cut3, cur_e, stbp, sa, T, cur_n, invp, E);
  }

  const int gblocks = (E + TE - 1) / TE;
  for (int k = 0; k < 3; ++k) {
    size_t u0 = (size_t)(k * 2 + 0), u1 = u0 + 1;
#define GMLP_ARGS                                                                          \
    nf, ef, rbf, src, dst, stbp, sa, off_e, cnt_e, atoms, invp,                            \
    ptbWs + (size_t)k * 4096, ptbGs + (size_t)k * 4096, peWs, eB,                          \
    pW0s + u0 * 384 * 128, pG0s + u0 * 384 * 128, pW1s + u0 * 128 * 128,                   \
    pG1s + u0 * 128 * 128, pW2s + u0 * 128 * 128, pG2s + u0 * 128 * 128,                   \
    B0 + u0 * 128, Gb0 + u0 * 128, B1 + u0 * 128, Gb1 + u0 * 128, B2 + u0 * 128,           \
    Gb2 + u0 * 128, pWTs + u0 * 4096,                                                      \
    pW0s + u1 * 384 * 128, pG0s + u1 * 384 * 128, pW1s + u1 * 128 * 128,                   \
    pG1s + u1 * 128 * 128, pW2s + u1 * 128 * 128, pG2s + u1 * 128 * 128,                   \
    B0 + u1 * 128, Gb0 + u1 * 128, B1 + u1 * 128, Gb1 + u1 * 128, B2 + u1 * 128,           \
    Gb2 + u1 * 128, pWTs + u1 * 4096,                                                      \
    mbuf, E, k < 2 ? 1 : 0
    if (k == 0) gmlp_fused<1><<<gblocks, 512, 0, stream>>>(GMLP_ARGS);
    else        gmlp_fused<0><<<gblocks, 512, 0, stream>>>(GMLP_ARGS);
#undef GMLP_ARGS
    int nk = k < 2 ? k + 1 : 0;
    node_gather_kernel<<<(N + 1) / 2, 256, 0, stream>>>(
        nf, mbuf, off_n, cnt_n, taW + (size_t)nk * 128 * 9, taB + (size_t)nk * 9,
        atoms, N, k < 2 ? 1 : 0);
  }

  int nchunks = (N + 255) / 256;
  mean_kernel<<<nchunks, 256, 0, stream>>>(nf, part, N);
  final_kernel<<<1, 128, 0, stream>>>(part, nchunks, (float)N, fW0, fb0, fW1, fb1, fW2, fb2,
                                      (float*)d_out);
}

// Round 17
// 488.840 us; speedup vs baseline: 1.0527x; 1.0072x over previous
//
#include <hip/hip_runtime.h>
#include <stdint.h>

typedef __attribute__((ext_vector_type(8))) short bf16x8;
typedef __attribute__((ext_vector_type(4))) float f32x4;
typedef __attribute__((ext_vector_type(4))) uint32_t u32x4;
typedef unsigned short ushort;

#define XSS 392   // xs row stride (shorts)
#define HSS 144   // hs/gs row stride (shorts); swizzle mask = ((row>>2)&3)*40
#define TE 32

// ---------------- helpers ----------------
__device__ __forceinline__ float sigm(float x) { return __fdividef(1.0f, 1.0f + __expf(-x)); }
__device__ __forceinline__ float silu(float x) { return __fdividef(x, 1.0f + __expf(-x)); }
__device__ __forceinline__ short f2bf(float f) {  // RNE f32->bf16 (pack path)
  uint32_t u = __float_as_uint(f);
  u = (u + 0x7fffu + ((u >> 16) & 1u)) >> 16;
  return (short)u;
}
__device__ __forceinline__ uint32_t cvt2(float lo, float hi) {
  uint32_t d;
  asm("v_cvt_pk_bf16_f32 %0, %1, %2" : "=v"(d) : "v"(lo), "v"(hi));
  return d;
}
__device__ __forceinline__ short f2bf1(float f) { return (short)cvt2(f, f); }

// fast hardware trig (args ≤ ~30 rad; ~1e-6 abs err — fine at bf16 tolerance)
__device__ __forceinline__ float jl_eval(int l, float x) {
  float s, c;
  __sincosf(x, &s, &c);
  float ix = 1.0f / x, ix2 = ix * ix;
  if (l == 0) return s * ix;
  if (l == 1) return s * ix2 - c * ix;
  if (l == 2) return (3.0f * ix2 * ix - ix) * s - 3.0f * ix2 * c;
  return (15.0f * ix2 * ix2 - 6.0f * ix2) * s - (15.0f * ix2 * ix - ix) * c;
}

// ---------------- setup1: node_init + edge_geom + CSR counts ----------------
__global__ void setup1_kernel(const int* __restrict__ ntb, const float* __restrict__ emb,
                              float* __restrict__ nf, int N,
                              const float* __restrict__ pos, const int* __restrict__ src,
                              const int* __restrict__ dst, float* __restrict__ bvec,
                              float* __restrict__ bdist, float* __restrict__ rbf,
                              float* __restrict__ cut3, int E,
                              const int* __restrict__ t_src, int* __restrict__ cnt_e,
                              int* __restrict__ cnt_n, int T) {
  int i = blockIdx.x * 256 + threadIdx.x;
  if (i < N * 128) {
    int n = i >> 7, c = i & 127;
    nf[i] = emb[ntb[n] * 128 + c];
  }
  if (i < E) {
    int s = src[i], d = dst[i];
    float dx = pos[d * 3 + 0] - pos[s * 3 + 0];
    float dy = pos[d * 3 + 1] - pos[s * 3 + 1];
    float dz = pos[d * 3 + 2] - pos[s * 3 + 2];
    float r = sqrtf(dx * dx + dy * dy + dz * dz + 1e-12f);
    bvec[i * 3 + 0] = dx; bvec[i * 3 + 1] = dy; bvec[i * 3 + 2] = dz;
    bdist[i] = r;
    const float roots[3][3] = {
        {3.141592653589793f, 6.283185307179586f, 9.42477796076938f},
        {4.493409457909064f, 7.725251836937707f, 10.904121659428899f},
        {5.763459196894550f, 9.095011330476355f, 12.322940970566582f}};
#pragma unroll
    for (int l = 0; l < 3; ++l) {
#pragma unroll
      for (int n = 0; n < 3; ++n) {
        float root = roots[l][n];
        float x = r * (root * 0.2f);
        float norm;
        if (l == 0) norm = 1.0f / root;
        else if (l == 1) norm = 1.0f / sqrtf(1.0f + root * root);
        else {
          float t = 3.0f * root / (3.0f - root * root);
          norm = fabsf(t - root) / (root * root * sqrtf(1.0f + t * t));
        }
        rbf[i * 9 + l * 3 + n] = jl_eval(l, x) * (0.12649110640673518f / norm);
      }
    }
    float xx = r * 0.25f;
    float x3 = xx * xx * xx;
    cut3[i] = 1.0f - 6.0f * x3 * xx * xx + 15.0f * x3 * xx - 10.0f * x3;
    atomicAdd(&cnt_n[d], 1);
  }
  if (i < T) atomicAdd(&cnt_e[t_src[i]], 1);
}

// ---------------- setup2: block scans + atoms(k=0) ----------------
__device__ void scan_chunk(const int* __restrict__ in, int* __restrict__ incl,
                           int* __restrict__ bsum, int L, int b) {
  __shared__ int sm[256];
  int i = b * 256 + threadIdx.x;
  int v = i < L ? in[i] : 0;
  sm[threadIdx.x] = v;
  __syncthreads();
  for (int st = 1; st < 256; st <<= 1) {
    int t = threadIdx.x >= st ? sm[threadIdx.x - st] : 0;
    __syncthreads();
    sm[threadIdx.x] += t;
    __syncthreads();
  }
  if (i < L) incl[i] = sm[threadIdx.x];
  if (threadIdx.x == 255) bsum[b] = sm[255];
}

__global__ void setup2_kernel(const int* __restrict__ cnt_e, int* __restrict__ incl_e,
                              int* __restrict__ bsum_e, int ebk, int E,
                              const int* __restrict__ cnt_n, int* __restrict__ incl_n,
                              int* __restrict__ bsum_n, int nbk, int N,
                              const float* __restrict__ nf, const float* __restrict__ taW,
                              const float* __restrict__ taB, float* __restrict__ atoms) {
  int b = blockIdx.x;
  if (b < ebk) scan_chunk(cnt_e, incl_e, bsum_e, E, b);
  else if (b < ebk + nbk) scan_chunk(cnt_n, incl_n, bsum_n, N, b - ebk);
  int i = b * 256 + threadIdx.x;
  if (i < N * 9) {
    int n = i / 9, d = i - n * 9;
    float acc = taB[d];
    for (int c = 0; c < 128; ++c) acc += nf[n * 128 + c] * taW[c * 9 + d];
    atoms[i] = sigm(acc);
  }
}

__global__ void scan_top2_kernel(int* __restrict__ bsum_e, int ne, int* __restrict__ bsum_n,
                                 int nn) {
  __shared__ int sm[1024];
  int* bs = blockIdx.x == 0 ? bsum_e : bsum_n;
  int nb = blockIdx.x == 0 ? ne : nn;
  int tid = threadIdx.x;
  int orig = tid < nb ? bs[tid] : 0;
  sm[tid] = orig;
  __syncthreads();
  for (int st = 1; st < 1024; st <<= 1) {
    int t = tid >= st ? sm[tid - st] : 0;
    __syncthreads();
    sm[tid] += t;
    __syncthreads();
  }
  if (tid < nb) bs[tid] = sm[tid] - orig;
}

__global__ void fin2_kernel(const int* __restrict__ cnt_e, const int* __restrict__ incl_e,
                            const int* __restrict__ bsum_e, int ebk, int* __restrict__ off_e,
                            int* __restrict__ cur_e, int E, const int* __restrict__ cnt_n,
                            const int* __restrict__ incl_n, const int* __restrict__ bsum_n,
                            int* __restrict__ off_n, int* __restrict__ cur_n, int N) {
  int b = blockIdx.x;
  if (b < ebk) {
    int i = b * 256 + threadIdx.x;
    if (i < E) {
      int o = incl_e[i] - cnt_e[i] + bsum_e[b];
      off_e[i] = o; cur_e[i] = o;
    }
  } else {
    int bb = b - ebk;
    int i = bb * 256 + threadIdx.x;
    if (i < N) {
      int o = incl_n[i] - cnt_n[i] + bsum_n[bb];
      off_n[i] = o; cur_n[i] = o;
    }
  }
}

// build: triplet precompute into CSR-sorted slots + inverse dst-permutation
__global__ void build_kernel(const int* __restrict__ t_src, const int* __restrict__ t_dst,
                             const int* __restrict__ dst, const float* __restrict__ bvec,
                             const float* __restrict__ bdist, const float* __restrict__ rbf,
                             const float* __restrict__ cut3, int* __restrict__ cur_e,
                             float* __restrict__ stbp, int* __restrict__ sa, int T,
                             int* __restrict__ cur_n, int* __restrict__ invp, int E) {
  int t = blockIdx.x * 256 + threadIdx.x;
  if (t < T) {
    int i = t_src[t], j = t_dst[t];
    float ax = bvec[i * 3], ay = bvec[i * 3 + 1], az = bvec[i * 3 + 2];
    float bx = bvec[j * 3], by = bvec[j * 3 + 1], bz = bvec[j * 3 + 2];
    float ct = (ax * bx + ay * by + az * bz) / (bdist[i] * bdist[j]);
    float tw = cut3[i] * cut3[j];
    float sh[3];
    sh[0] = 0.28209479177387814f * tw;
    sh[1] = 0.4886025119029199f * ct * tw;
    sh[2] = 0.31539156525252005f * (3.0f * ct * ct - 1.0f) * tw;
    int pos = atomicAdd(&cur_e[i], 1);
#pragma unroll
    for (int l = 0; l < 3; ++l)
#pragma unroll
      for (int n = 0; n < 3; ++n)
        stbp[(size_t)pos * 9 + l * 3 + n] = rbf[j * 9 + l * 3 + n] * sh[l];
    sa[pos] = dst[j];
  }
  if (t < E) {
    int pos = atomicAdd(&cur_n[dst[t]], 1);
    invp[t] = pos;
  }
}

// ---------------- weight packing (gmlp + tb + WT + eW + cnt-zero, one launch) -----------
__device__ void pack_one(const float* __restrict__ Wf, short* __restrict__ Wp, int K, int rr) {
  int per = 8 * (K / 32) * 64;
  int u = rr / per, r2 = rr - u * per;
  int lane = r2 & 63, tile = r2 >> 6;
  int kt = tile % (K / 32), nt = tile / (K / 32);
  int n = nt * 16 + (lane & 15);
  int k0 = kt * 32 + (lane >> 4) * 8;
  const float* s = Wf + (size_t)u * K * 128;
  bf16x8 v;
#pragma unroll
  for (int e = 0; e < 8; ++e) v[e] = f2bf(s[(size_t)(k0 + e) * 128 + n]);
  *(bf16x8*)(Wp + (size_t)u * K * 128 + (size_t)tile * 512 + lane * 8) = v;
}

__device__ void pack_pad9(const float* __restrict__ s, short* __restrict__ dp9, int l2) {
  int lane = l2 & 63, tile = l2 >> 6;
  int n = tile * 16 + (lane & 15);
  int k0 = (lane >> 4) * 8;
  bf16x8 v;
#pragma unroll
  for (int e = 0; e < 8; ++e)
    v[e] = (k0 + e < 9) ? f2bf(s[(size_t)(k0 + e) * 128 + n]) : (short)0;
  *(bf16x8*)(dp9 + tile * 512 + lane * 8) = v;
}

__global__ void pack_all_kernel(const float* __restrict__ W0, const float* __restrict__ G0,
                                const float* __restrict__ W1, const float* __restrict__ G1,
                                const float* __restrict__ W2, const float* __restrict__ G2,
                                const float* __restrict__ tbW, const float* __restrict__ tbG,
                                const float* __restrict__ WT, const float* __restrict__ eW,
                                short* __restrict__ pW0, short* __restrict__ pG0,
                                short* __restrict__ pW1, short* __restrict__ pG1,
                                short* __restrict__ pW2, short* __restrict__ pG2,
                                short* __restrict__ ptbW, short* __restrict__ ptbG,
                                short* __restrict__ pWT, short* __restrict__ peW,
                                int* __restrict__ cnt_all, int lenEN) {
  int idx = blockIdx.x * 256 + threadIdx.x;
  // fold cnt zeroing in (replaces a hipMemsetAsync dispatch)
  for (int z = idx; z < lenEN; z += gridDim.x * 256) cnt_all[z] = 0;
  const int t384 = 6 * 8 * 12 * 64, t128 = 6 * 8 * 4 * 64;
  if (idx < t384) { pack_one(W0, pW0, 384, idx); return; }
  if (idx < 2 * t384) { pack_one(G0, pG0, 384, idx - t384); return; }
  int j = idx - 2 * t384;
  if (j < t128) { pack_one(W1, pW1, 128, j); return; }
  if (j < 2 * t128) { pack_one(G1, pG1, 128, j - t128); return; }
  if (j < 3 * t128) { pack_one(W2, pW2, 128, j - 2 * t128); return; }
  if (j < 4 * t128) { pack_one(G2, pG2, 128, j - 3 * t128); return; }
  j -= 4 * t128;
  if (j < 3072) {  // tb weights: 3 k-blocks x {W,G} x 512
    int kb = j >> 10;
    int w2 = (j >> 9) & 1;
    int l2 = j & 511;
    const float* s = (w2 ? tbG : tbW) + (size_t)kb * 9 * 128;
    short* dp = (w2 ? ptbG : ptbW) + (size_t)kb * 4096;
    pack_pad9(s, dp, l2);
    return;
  }
  j -= 3072;
  if (j < 3072) {  // WT: 6 units x 512
    int u = j >> 9;
    pack_pad9(WT + (size_t)u * 9 * 128, pWT + (size_t)u * 4096, j & 511);
    return;
  }
  j -= 3072;
  if (j < 512) pack_pad9(eW, peW, j);  // edge-embedding weight
}

// ---------------- fused gated-MLP on MFMA ----------------
__device__ __forceinline__ f32x4 mfma16(bf16x8 a, bf16x8 b, f32x4 c) {
  return __builtin_amdgcn_mfma_f32_16x16x32_bf16(a, b, c, 0, 0, 0);
}

__device__ __forceinline__ void store_hg(short* hsb, short* gsb, int wave, int lane,
                                         const f32x4 (&aW)[2], const f32x4 (&aG)[2]) {
  const int lrow = lane & 15, lk = lane >> 4;
  const int colx = (wave * 16 + lrow) ^ (lk * 40);
#pragma unroll
  for (int mt = 0; mt < 2; ++mt)
#pragma unroll
    for (int rg = 0; rg < 4; ++rg) {
      int row = mt * 16 + lk * 4 + rg;
      hsb[row * HSS + colx] = f2bf1(silu(aW[mt][rg]));
      gsb[row * HSS + colx] = f2bf1(silu(aG[mt][rg]));
    }
}

__device__ __forceinline__ void layer128w(const short* hin, const short* gin,
                                          const short* __restrict__ pW,
                                          const short* __restrict__ pG,
                                          const float* __restrict__ Bh,
                                          const float* __restrict__ Bg, int wave, int lane,
                                          f32x4 (&aW)[2], f32x4 (&aG)[2]) {
  const int lrow = lane & 15, lk = lane >> 4;
  const int s0 = (lrow >> 2) & 3;
  float bw = Bh[wave * 16 + lrow], bg = Bg[wave * 16 + lrow];
  aW[0] = {bw, bw, bw, bw}; aW[1] = aW[0];
  aG[0] = {bg, bg, bg, bg}; aG[1] = aG[0];
#pragma unroll
  for (int kt = 0; kt < 4; ++kt) {
    int aoff = (kt * 32 + lk * 8) ^ (s0 * 40);
    bf16x8 ah0 = *(const bf16x8*)(hin + (size_t)lrow * HSS + aoff);
    bf16x8 ah1 = *(const bf16x8*)(hin + (size_t)(16 + lrow) * HSS + aoff);
    bf16x8 ag0 = *(const bf16x8*)(gin + (size_t)lrow * HSS + aoff);
    bf16x8 ag1 = *(const bf16x8*)(gin + (size_t)(16 + lrow) * HSS + aoff);
    bf16x8 bw8 = *(const bf16x8*)(pW + (size_t)(wave * 4 + kt) * 512 + lane * 8);
    bf16x8 bg8 = *(const bf16x8*)(pG + (size_t)(wave * 4 + kt) * 512 + lane * 8);
    aW[0] = mfma16(ah0, bw8, aW[0]);
    aW[1] = mfma16(ah1, bw8, aW[1]);
    aG[0] = mfma16(ag0, bg8, aG[0]);
    aG[1] = mfma16(ag1, bg8, aG[1]);
  }
}

__device__ __forceinline__ void run_chain(
    const short* xsb, short* hsb, short* gsb,
    const short* __restrict__ pW0, const short* __restrict__ pG0,
    const short* __restrict__ pW1, const short* __restrict__ pG1,
    const short* __restrict__ pW2, const short* __restrict__ pG2,
    const float* __restrict__ B0, const float* __restrict__ Gb0,
    const float* __restrict__ B1, const float* __restrict__ Gb1,
    const float* __restrict__ B2, const float* __restrict__ Gb2,
    int wave, int lane, f32x4 (&aW)[2], f32x4 (&aG)[2]) {
  const int lrow = lane & 15, lk = lane >> 4;
  const int s0 = (lrow >> 2) & 3;
  {
    float bw = B0[wave * 16 + lrow], bg = Gb0[wave * 16 + lrow];
    aW[0] = {bw, bw, bw, bw}; aW[1] = aW[0];
    aG[0] = {bg, bg, bg, bg}; aG[1] = aG[0];
  }
#pragma unroll
  for (int kt = 0; kt < 12; ++kt) {
    int al = kt * 32 + lk * 8;
    int aoff = (al < 256) ? al : (256 + ((al - 256) ^ (s0 << 4)));  // ef region swizzled
    bf16x8 a0 = *(const bf16x8*)(xsb + (size_t)lrow * XSS + aoff);
    bf16x8 a1 = *(const bf16x8*)(xsb + (size_t)(16 + lrow) * XSS + aoff);
    bf16x8 bw8 = *(const bf16x8*)(pW0 + (size_t)(wave * 12 + kt) * 512 + lane * 8);
    bf16x8 bg8 = *(const bf16x8*)(pG0 + (size_t)(wave * 12 + kt) * 512 + lane * 8);
    aW[0] = mfma16(a0, bw8, aW[0]);
    aW[1] = mfma16(a1, bw8, aW[1]);
    aG[0] = mfma16(a0, bg8, aG[0]);
    aG[1] = mfma16(a1, bg8, aG[1]);
  }
  store_hg(hsb, gsb, wave, lane, aW, aG);
  __syncthreads();
  layer128w(hsb, gsb, pW1, pG1, B1, Gb1, wave, lane, aW, aG);
  __syncthreads();
  store_hg(hsb, gsb, wave, lane, aW, aG);
  __syncthreads();
  layer128w(hsb, gsb, pW2, pG2, B2, Gb2, wave, lane, aW, aG);
}

template <int ISK0>
__global__ __launch_bounds__(512, 6) void gmlp_fused(
    const float* __restrict__ nf, float* __restrict__ ef, const float* __restrict__ rbf,
    const int* __restrict__ src, const int* __restrict__ dst,
    const float* __restrict__ stbp, const int* __restrict__ sa,
    const int* __restrict__ off_e, const int* __restrict__ cnt_e,
    const float* __restrict__ atoms, const int* __restrict__ invp,
    const short* __restrict__ ptbW, const short* __restrict__ ptbG,
    const short* __restrict__ peW, const float* __restrict__ eB,
    const short* __restrict__ pW0a, const short* __restrict__ pG0a,
    const short* __restrict__ pW1a, const short* __restrict__ pG1a,
    const short* __restrict__ pW2a, const short* __restrict__ pG2a,
    const float* __restrict__ B0a, const float* __restrict__ Gb0a,
    const float* __restrict__ B1a, const float* __restrict__ Gb1a,
    const float* __restrict__ B2a, const float* __restrict__ Gb2a,
    const short* __restrict__ pWTa,
    const short* __restrict__ pW0b, const short* __restrict__ pG0b,
    const short* __restrict__ pW1b, const short* __restrict__ pG1b,
    const short* __restrict__ pW2b, const short* __restrict__ pG2b,
    const float* __restrict__ B0b, const float* __restrict__ Gb0b,
    const float* __restrict__ B1b, const float* __restrict__ Gb1b,
    const float* __restrict__ B2b, const float* __restrict__ Gb2b,
    const short* __restrict__ pWTb,
    float* __restrict__ mbuf, int E, int writeEf) {
  __shared__ __align__(16) short xs[32][XSS];
  __shared__ __align__(16) short hs[32 * HSS];
  __shared__ __align__(16) short gs[32 * HSS];
  __shared__ __align__(16) short nbl[32][40];  // K=32-padded nb, bf16
  __shared__ __align__(16) short rbl[32][40];  // K=32-padded rbf, bf16
  __shared__ int invs[32];
  const int tid = threadIdx.x;
  const int e0 = blockIdx.x * TE;
  const int r = tid >> 4, q = tid & 15;
  int eg = e0 + r; if (eg >= E) eg = E - 1;

  // ---- fused nb_reduce -> bf16 nbl (zero-pad K 9..31) ----
  {
    float acc = 0.f;
    if (q < 9) {
      int o = off_e[eg], c = cnt_e[eg];
      for (int pp = o; pp < o + c; ++pp)
        acc += stbp[(size_t)pp * 9 + q] * atoms[(size_t)sa[pp] * 9 + q];
    }
    nbl[r][q] = (q < 9) ? f2bf1(acc) : (short)0;
    nbl[r][q + 16] = 0;
  }
  // ---- gather nf segments as bf16; rbf -> rbl bf16 ----
  {
    const float* sp0 = nf + (size_t)src[eg] * 128;
    const float* sp1 = nf + (size_t)dst[eg] * 128;
#pragma unroll
    for (int seg = 0; seg < 2; ++seg) {
      const float* sp = seg == 0 ? sp0 : sp1;
      float4 f0 = *(const float4*)(sp + q * 8);
      float4 f1 = *(const float4*)(sp + q * 8 + 4);
      u32x4 v = {cvt2(f0.x, f0.y), cvt2(f0.z, f0.w), cvt2(f1.x, f1.y), cvt2(f1.z, f1.w)};
      *(u32x4*)&xs[r][seg * 128 + q * 8] = v;
    }
    for (int idx = tid; idx < 32 * 32; idx += 512) {
      int rr = idx >> 5, d = idx & 31;
      int ee = e0 + rr; if (ee >= E) ee = E - 1;
      rbl[rr][d] = (d < 9) ? f2bf1(rbf[ee * 9 + d]) : (short)0;
    }
    if (tid < 32) {
      int ee = e0 + tid; if (ee >= E) ee = E - 1;
      invs[tid] = invp[ee];
    }
  }
  __syncthreads();

  const int wave = tid >> 6;
  const int lane = tid & 63;
  const int lrow = lane & 15, lk = lane >> 4;
  const int col = wave * 16 + lrow;
  const int cs = 256 + (col ^ (lk << 4));
  f32x4 aW[2], aG[2];
  float efb[2][4];  // ef + tb_update base, carried in registers through chain 0

  // ---- tb_update via MFMA (+ compile-time edge_emb fusion at k=0) ----
  {
    bf16x8 ta0 = *(const bf16x8*)&nbl[lrow][lk * 8];
    bf16x8 ta1 = *(const bf16x8*)&nbl[16 + lrow][lk * 8];
    bf16x8 tbw = *(const bf16x8*)(ptbW + wave * 512 + lane * 8);
    bf16x8 tbg = *(const bf16x8*)(ptbG + wave * 512 + lane * 8);
    f32x4 z = {0.f, 0.f, 0.f, 0.f};
    f32x4 tW0 = mfma16(ta0, tbw, z), tW1 = mfma16(ta1, tbw, z);
    f32x4 tG0 = mfma16(ta0, tbg, z), tG1 = mfma16(ta1, tbg, z);
    if (ISK0) {  // ef = silu(rbf @ eW + eB), computed in-place
      bf16x8 ra0 = *(const bf16x8*)&rbl[lrow][lk * 8];
      bf16x8 ra1 = *(const bf16x8*)&rbl[16 + lrow][lk * 8];
      bf16x8 ew8 = *(const bf16x8*)(peW + wave * 512 + lane * 8);
      float ebv = eB[col];
      f32x4 ec = {ebv, ebv, ebv, ebv};
      f32x4 e0v = mfma16(ra0, ew8, ec);
      f32x4 e1v = mfma16(ra1, ew8, ec);
#pragma unroll
      for (int mt = 0; mt < 2; ++mt)
#pragma unroll
        for (int rg = 0; rg < 4; ++rg) {
          int row = mt * 16 + lk * 4 + rg;
          float tw = mt == 0 ? tW0[rg] : tW1[rg];
          float tg = mt == 0 ? tG0[rg] : tG1[rg];
          float base = silu(mt == 0 ? e0v[rg] : e1v[rg]) + silu(tw) * sigm(tg);
          efb[mt][rg] = base;
          xs[row][cs] = f2bf1(base);
        }
    } else {
#pragma unroll
      for (int mt = 0; mt < 2; ++mt)
#pragma unroll
        for (int rg = 0; rg < 4; ++rg) {
          int row = mt * 16 + lk * 4 + rg;
          int ec2 = e0 + row; if (ec2 >= E) ec2 = E - 1;
          float tw = mt == 0 ? tW0[rg] : tW1[rg];
          float tg = mt == 0 ? tG0[rg] : tG1[rg];
          float base = ef[(size_t)ec2 * 128 + col] + silu(tw) * sigm(tg);
          efb[mt][rg] = base;
          xs[row][cs] = f2bf1(base);
        }
    }
  }
  __syncthreads();

  // ---- chain 0: edge update ----
  run_chain(&xs[0][0], hs, gs, pW0a, pG0a, pW1a, pG1a, pW2a, pG2a,
            B0a, Gb0a, B1a, Gb1a, B2a, Gb2a, wave, lane, aW, aG);
  {
    bf16x8 ra0 = *(const bf16x8*)&rbl[lrow][lk * 8];
    bf16x8 ra1 = *(const bf16x8*)&rbl[16 + lrow][lk * 8];
    bf16x8 wtb = *(const bf16x8*)(pWTa + wave * 512 + lane * 8);
    f32x4 z = {0.f, 0.f, 0.f, 0.f};
    f32x4 wv0 = mfma16(ra0, wtb, z), wv1 = mfma16(ra1, wtb, z);
#pragma unroll
    for (int mt = 0; mt < 2; ++mt)
#pragma unroll
      for (int rg = 0; rg < 4; ++rg) {
        int row = mt * 16 + lk * 4 + rg;
        int e = e0 + row;
        float wv = mt == 0 ? wv0[rg] : wv1[rg];
        float v = silu(aW[mt][rg]) * sigm(aG[mt][rg]) * wv;
        float nv = efb[mt][rg] + v;
        if (e < E && writeEf) ef[(size_t)e * 128 + col] = nv;
        xs[row][cs] = f2bf1(nv);
      }
  }
  __syncthreads();

  // ---- chain 1: node update ----
  run_chain(&xs[0][0], hs, gs, pW0b, pG0b, pW1b, pG1b, pW2b, pG2b,
            B0b, Gb0b, B1b, Gb1b, B2b, Gb2b, wave, lane, aW, aG);
  {
    bf16x8 ra0 = *(const bf16x8*)&rbl[lrow][lk * 8];
    bf16x8 ra1 = *(const bf16x8*)&rbl[16 + lrow][lk * 8];
    bf16x8 wtb = *(const bf16x8*)(pWTb + wave * 512 + lane * 8);
    f32x4 z = {0.f, 0.f, 0.f, 0.f};
    f32x4 wv0 = mfma16(ra0, wtb, z), wv1 = mfma16(ra1, wtb, z);
#pragma unroll
    for (int mt = 0; mt < 2; ++mt)
#pragma unroll
      for (int rg = 0; rg < 4; ++rg) {
        int row = mt * 16 + lk * 4 + rg;
        int e = e0 + row;
        float wv = mt == 0 ? wv0[rg] : wv1[rg];
        float v = silu(aW[mt][rg]) * sigm(aG[mt][rg]) * wv;
        if (e < E) mbuf[(size_t)invs[row] * 128 + col] = v;  // dst-sorted position
      }
  }
}

// ---- node gather (sequential, dst-sorted mbuf) + parallel fused atoms ----
__global__ void node_gather_kernel(float* __restrict__ nf, const float* __restrict__ mbuf,
                                   const int* __restrict__ off_n, const int* __restrict__ cnt_n,
                                   const float* __restrict__ taW, const float* __restrict__ taB,
                                   float* __restrict__ atoms, int N, int doAtoms) {
  __shared__ float red[2][9][128];
  int half = threadIdx.x >> 7, c = threadIdx.x & 127;
  int n = blockIdx.x * 2 + half;
  float v = 0.f;
  if (n < N) {
    int o = off_n[n], cnt = cnt_n[n];
    float acc = 0.f;
    for (int p = 0; p < cnt; ++p) acc += mbuf[(size_t)(o + p) * 128 + c];
    v = nf[(size_t)n * 128 + c] + acc;
    nf[(size_t)n * 128 + c] = v;
  }
  if (doAtoms) {
#pragma unroll
    for (int d = 0; d < 9; ++d) red[half][d][c] = (n < N) ? v * taW[c * 9 + d] : 0.f;
    for (int s = 64; s >= 1; s >>= 1) {
      __syncthreads();
      for (int idx = threadIdx.x; idx < 2 * 9 * s; idx += 256) {
        int h = idx / (9 * s), rem = idx - h * 9 * s;
        int d = rem / s, j = rem - d * s;
        red[h][d][j] += red[h][d][j + s];
      }
    }
    __syncthreads();
    if (threadIdx.x < 18) {
      int h = threadIdx.x / 9, d = threadIdx.x - h * 9;
      int nn = blockIdx.x * 2 + h;
      if (nn < N) atoms[nn * 9 + d] = sigm(red[h][d][0] + taB[d]);
    }
  }
}

// ---------------- readout ----------------
__global__ void mean_kernel(const float* __restrict__ nf, float* __restrict__ partial, int N) {
  __shared__ float sm[256];
  int n0 = blockIdx.x * 256;
  int col = threadIdx.x & 127, half = threadIdx.x >> 7;
  int nend = n0 + 256 < N ? n0 + 256 : N;
  float s = 0.f;
  for (int n = n0 + half; n < nend; n += 2) s += nf[n * 128 + col];
  sm[threadIdx.x] = s;
  __syncthreads();
  if (threadIdx.x < 128)
    partial[blockIdx.x * 128 + threadIdx.x] = sm[threadIdx.x] + sm[threadIdx.x + 128];
}

__global__ void final_kernel(const float* __restrict__ partial, int nchunks, float Nf,
                             const float* __restrict__ fW0, const float* __restrict__ fb0,
                             const float* __restrict__ fW1, const float* __restrict__ fb1,
                             const float* __restrict__ fW2, const float* __restrict__ fb2,
                             float* __restrict__ out) {
  __shared__ float v[128], h[128], red[128];
  int tid = threadIdx.x;  // 128 threads
  float s = 0.f;
  for (int b = 0; b < nchunks; ++b) s += partial[b * 128 + tid];
  v[tid] = s / Nf;
  __syncthreads();
  float acc = fb0[tid];
  for (int c = 0; c < 128; ++c) acc += v[c] * fW0[c * 128 + tid];
  h[tid] = silu(acc);
  __syncthreads();
  acc = fb1[tid];
  for (int c = 0; c < 128; ++c) acc += h[c] * fW1[c * 128 + tid];
  __syncthreads();
  v[tid] = silu(acc);
  __syncthreads();
  red[tid] = v[tid] * fW2[tid];
  __syncthreads();
  for (int st = 64; st > 0; st >>= 1) {
    if (tid < st) red[tid] += red[tid + st];
    __syncthreads();
  }
  if (tid == 0) out[0] = red[0] + fb2[0];
}

// ---------------- launch ----------------
extern "C" void kernel_launch(void* const* d_in, const int* in_sizes, int n_in,
                              void* d_out, int out_size, void* d_ws, size_t ws_size,
                              hipStream_t stream) {
  const float* pos = (const float*)d_in[0];
  const int* node_type = (const int*)d_in[1];
  const int* src = (const int*)d_in[2];
  const int* dst = (const int*)d_in[3];
  const int* t_src = (const int*)d_in[4];
  const int* t_dst = (const int*)d_in[5];
  const float* emb = (const float*)d_in[6];
  const float* eW = (const float*)d_in[7];
  const float* eB = (const float*)d_in[8];
  const float* taW = (const float*)d_in[9];
  const float* taB = (const float*)d_in[10];
  const float* tbW = (const float*)d_in[11];
  const float* tbG = (const float*)d_in[12];
  const float* W0 = (const float*)d_in[13]; const float* B0 = (const float*)d_in[14];
  const float* W1 = (const float*)d_in[15]; const float* B1 = (const float*)d_in[16];
  const float* W2 = (const float*)d_in[17]; const float* B2 = (const float*)d_in[18];
  const float* G0 = (const float*)d_in[19]; const float* Gb0 = (const float*)d_in[20];
  const float* G1 = (const float*)d_in[21]; const float* Gb1 = (const float*)d_in[22];
  const float* G2 = (const float*)d_in[23]; const float* Gb2 = (const float*)d_in[24];
  const float* WT = (const float*)d_in[25];
  const float* fW0 = (const float*)d_in[26]; const float* fb0 = (const float*)d_in[27];
  const float* fW1 = (const float*)d_in[28]; const float* fb1 = (const float*)d_in[29];
  const float* fW2 = (const float*)d_in[30]; const float* fb2 = (const float*)d_in[31];

  const int N = in_sizes[1];
  const int E = in_sizes[2];
  const int T = in_sizes[4];

  char* p = (char*)d_ws;
  auto alloc = [&](size_t bytes) -> char* {
    char* r = p;
    p += (bytes + 255) & ~(size_t)255;
    return r;
  };
  float*  nf    = (float*)alloc((size_t)N * 128 * 4);
  float*  ef    = (float*)alloc((size_t)E * 128 * 4);
  float*  mbuf  = (float*)alloc((size_t)E * 128 * 4);
  float*  rbf   = (float*)alloc((size_t)E * 9 * 4);
  float*  bvec  = (float*)alloc((size_t)E * 3 * 4);
  float*  bdist = (float*)alloc((size_t)E * 4);
  float*  cut3  = (float*)alloc((size_t)E * 4);
  float*  stbp  = (float*)alloc((size_t)T * 9 * 4);
  int*    sa    = (int*)alloc((size_t)T * 4);
  float*  atoms = (float*)alloc((size_t)N * 9 * 4);
  float*  part  = (float*)alloc((size_t)64 * 128 * 4);
  int* cnt_all = (int*)alloc((size_t)(E + N) * 4);
  int* cnt_e = cnt_all, *cnt_n = cnt_all + E;
  int* incl_e = (int*)alloc((size_t)E * 4);
  int* incl_n = (int*)alloc((size_t)N * 4);
  int* off_e  = (int*)alloc((size_t)E * 4);
  int* off_n  = (int*)alloc((size_t)N * 4);
  int* cur_e  = (int*)alloc((size_t)E * 4);
  int* cur_n  = (int*)alloc((size_t)N * 4);
  int* invp   = (int*)alloc((size_t)E * 4);
  int* bsum_e = (int*)alloc((size_t)1024 * 4);
  int* bsum_n = (int*)alloc((size_t)1024 * 4);
  short* pW0s = (short*)alloc((size_t)6 * 384 * 128 * 2);
  short* pG0s = (short*)alloc((size_t)6 * 384 * 128 * 2);
  short* pW1s = (short*)alloc((size_t)6 * 128 * 128 * 2);
  short* pG1s = (short*)alloc((size_t)6 * 128 * 128 * 2);
  short* pW2s = (short*)alloc((size_t)6 * 128 * 128 * 2);
  short* pG2s = (short*)alloc((size_t)6 * 128 * 128 * 2);
  short* ptbWs = (short*)alloc((size_t)3 * 4096 * 2);
  short* ptbGs = (short*)alloc((size_t)3 * 4096 * 2);
  short* pWTs  = (short*)alloc((size_t)6 * 4096 * 2);
  short* peWs  = (short*)alloc((size_t)4096 * 2);
  (void)ws_size; (void)n_in; (void)out_size;

  const int ebk = (E + 255) / 256, nbk = (N + 255) / 256;

  pack_all_kernel<<<506, 256, 0, stream>>>(W0, G0, W1, G1, W2, G2, tbW, tbG, WT, eW,
                                           pW0s, pG0s, pW1s, pG1s, pW2s, pG2s,
                                           ptbWs, ptbGs, pWTs, peWs, cnt_all, E + N);
  {
    int g1 = N * 128; if (E > g1) g1 = E; if (T > g1) g1 = T;
    setup1_kernel<<<(g1 + 255) / 256, 256, 0, stream>>>(
        node_type, emb, nf, N, pos, src, dst, bvec, bdist, rbf, cut3, E, t_src, cnt_e, cnt_n, T);
  }
  {
    int g2 = (ebk + nbk) * 256; if (N * 9 > g2) g2 = N * 9;
    setup2_kernel<<<(g2 + 255) / 256, 256, 0, stream>>>(
        cnt_e, incl_e, bsum_e, ebk, E, cnt_n, incl_n, bsum_n, nbk, N, nf, taW, taB, atoms);
  }
  scan_top2_kernel<<<2, 1024, 0, stream>>>(bsum_e, ebk, bsum_n, nbk);
  fin2_kernel<<<ebk + nbk, 256, 0, stream>>>(cnt_e, incl_e, bsum_e, ebk, off_e, cur_e, E,
                                             cnt_n, incl_n, bsum_n, off_n, cur_n, N);
  {
    int g3 = T > E ? T : E;
    build_kernel<<<(g3 + 255) / 256, 256, 0, stream>>>(t_src, t_dst, dst, bvec, bdist, rbf,
                                                       cut3, cur_e, stbp, sa, T, cur_n, invp, E);
  }

  const int gblocks = (E + TE - 1) / TE;
  for (int k = 0; k < 3; ++k) {
    size_t u0 = (size_t)(k * 2 + 0), u1 = u0 + 1;
#define GMLP_ARGS                                                                          \
    nf, ef, rbf, src, dst, stbp, sa, off_e, cnt_e, atoms, invp,                            \
    ptbWs + (size_t)k * 4096, ptbGs + (size_t)k * 4096, peWs, eB,                          \
    pW0s + u0 * 384 * 128, pG0s + u0 * 384 * 128, pW1s + u0 * 128 * 128,                   \
    pG1s + u0 * 128 * 128, pW2s + u0 * 128 * 128, pG2s + u0 * 128 * 128,                   \
    B0 + u0 * 128, Gb0 + u0 * 128, B1 + u0 * 128, Gb1 + u0 * 128, B2 + u0 * 128,           \
    Gb2 + u0 * 128, pWTs + u0 * 4096,                                                      \
    pW0s + u1 * 384 * 128, pG0s + u1 * 384 * 128, pW1s + u1 * 128 * 128,                   \
    pG1s + u1 * 128 * 128, pW2s + u1 * 128 * 128, pG2s + u1 * 128 * 128,                   \
    B0 + u1 * 128, Gb0 + u1 * 128, B1 + u1 * 128, Gb1 + u1 * 128, B2 + u1 * 128,           \
    Gb2 + u1 * 128, pWTs + u1 * 4096,                                                      \
    mbuf, E, k < 2 ? 1 : 0
    if (k == 0) gmlp_fused<1><<<gblocks, 512, 0, stream>>>(GMLP_ARGS);
    else        gmlp_fused<0><<<gblocks, 512, 0, stream>>>(GMLP_ARGS);
#undef GMLP_ARGS
    int nk = k < 2 ? k + 1 : 0;
    node_gather_kernel<<<(N + 1) / 2, 256, 0, stream>>>(
        nf, mbuf, off_n, cnt_n, taW + (size_t)nk * 128 * 9, taB + (size_t)nk * 9,
        atoms, N, k < 2 ? 1 : 0);
  }

  int nchunks = (N + 255) / 256;
  mean_kernel<<<nchunks, 256, 0, stream>>>(nf, part, N);
  final_kernel<<<1, 128, 0, stream>>>(part, nchunks, (float)N, fW0, fb0, fW1, fb1, fW2, fb2,
                                      (float*)d_out);
}

// Round 18
// 471.857 us; speedup vs baseline: 1.0906x; 1.0360x over previous
//
#include <hip/hip_runtime.h>
#include <stdint.h>

typedef __attribute__((ext_vector_type(8))) short bf16x8;
typedef __attribute__((ext_vector_type(4))) float f32x4;
typedef __attribute__((ext_vector_type(4))) uint32_t u32x4;
typedef unsigned short ushort;

#define XSS 392   // xs row stride (shorts)
#define HSS 144   // hs/gs row stride (shorts); swizzle mask = ((row>>2)&3)*40
#define TE 32

// ---------------- helpers ----------------
__device__ __forceinline__ float sigm(float x) { return __fdividef(1.0f, 1.0f + __expf(-x)); }
__device__ __forceinline__ float silu(float x) { return __fdividef(x, 1.0f + __expf(-x)); }
// sigm(a)*sigm(g) with a single rcp; overflow -> 0 gives correct asymptote
__device__ __forceinline__ float sig2(float a, float g) {
  return __fdividef(1.0f, (1.0f + __expf(-a)) * (1.0f + __expf(-g)));
}
__device__ __forceinline__ short f2bf(float f) {  // RNE f32->bf16 (pack path)
  uint32_t u = __float_as_uint(f);
  u = (u + 0x7fffu + ((u >> 16) & 1u)) >> 16;
  return (short)u;
}
__device__ __forceinline__ float bf2f(ushort u) { return __uint_as_float(((uint32_t)u) << 16); }
__device__ __forceinline__ uint32_t cvt2(float lo, float hi) {
  uint32_t d;
  asm("v_cvt_pk_bf16_f32 %0, %1, %2" : "=v"(d) : "v"(lo), "v"(hi));
  return d;
}
__device__ __forceinline__ short f2bf1(float f) { return (short)cvt2(f, f); }

// fast hardware trig (args ≤ ~30 rad; ~1e-6 abs err — fine at bf16 tolerance)
__device__ __forceinline__ float jl_eval(int l, float x) {
  float s, c;
  __sincosf(x, &s, &c);
  float ix = 1.0f / x, ix2 = ix * ix;
  if (l == 0) return s * ix;
  if (l == 1) return s * ix2 - c * ix;
  if (l == 2) return (3.0f * ix2 * ix - ix) * s - 3.0f * ix2 * c;
  return (15.0f * ix2 * ix2 - 6.0f * ix2) * s - (15.0f * ix2 * ix - ix) * c;
}

// ---------------- setup1: node_init + edge_geom + CSR counts ----------------
__global__ void setup1_kernel(const int* __restrict__ ntb, const float* __restrict__ emb,
                              float* __restrict__ nf, int N,
                              const float* __restrict__ pos, const int* __restrict__ src,
                              const int* __restrict__ dst, float* __restrict__ bvec,
                              float* __restrict__ bdist, float* __restrict__ rbf,
                              float* __restrict__ cut3, int E,
                              const int* __restrict__ t_src, int* __restrict__ cnt_e,
                              int* __restrict__ cnt_n, int T) {
  int i = blockIdx.x * 256 + threadIdx.x;
  if (i < N * 128) {
    int n = i >> 7, c = i & 127;
    nf[i] = emb[ntb[n] * 128 + c];
  }
  if (i < E) {
    int s = src[i], d = dst[i];
    float dx = pos[d * 3 + 0] - pos[s * 3 + 0];
    float dy = pos[d * 3 + 1] - pos[s * 3 + 1];
    float dz = pos[d * 3 + 2] - pos[s * 3 + 2];
    float r = sqrtf(dx * dx + dy * dy + dz * dz + 1e-12f);
    bvec[i * 3 + 0] = dx; bvec[i * 3 + 1] = dy; bvec[i * 3 + 2] = dz;
    bdist[i] = r;
    const float roots[3][3] = {
        {3.141592653589793f, 6.283185307179586f, 9.42477796076938f},
        {4.493409457909064f, 7.725251836937707f, 10.904121659428899f},
        {5.763459196894550f, 9.095011330476355f, 12.322940970566582f}};
#pragma unroll
    for (int l = 0; l < 3; ++l) {
#pragma unroll
      for (int n = 0; n < 3; ++n) {
        float root = roots[l][n];
        float x = r * (root * 0.2f);
        float norm;
        if (l == 0) norm = 1.0f / root;
        else if (l == 1) norm = 1.0f / sqrtf(1.0f + root * root);
        else {
          float t = 3.0f * root / (3.0f - root * root);
          norm = fabsf(t - root) / (root * root * sqrtf(1.0f + t * t));
        }
        rbf[i * 9 + l * 3 + n] = jl_eval(l, x) * (0.12649110640673518f / norm);
      }
    }
    float xx = r * 0.25f;
    float x3 = xx * xx * xx;
    cut3[i] = 1.0f - 6.0f * x3 * xx * xx + 15.0f * x3 * xx - 10.0f * x3;
    atomicAdd(&cnt_n[d], 1);
  }
  if (i < T) atomicAdd(&cnt_e[t_src[i]], 1);
}

// ---------------- setup2: block scans + atoms(k=0) ----------------
__device__ void scan_chunk(const int* __restrict__ in, int* __restrict__ incl,
                           int* __restrict__ bsum, int L, int b) {
  __shared__ int sm[256];
  int i = b * 256 + threadIdx.x;
  int v = i < L ? in[i] : 0;
  sm[threadIdx.x] = v;
  __syncthreads();
  for (int st = 1; st < 256; st <<= 1) {
    int t = threadIdx.x >= st ? sm[threadIdx.x - st] : 0;
    __syncthreads();
    sm[threadIdx.x] += t;
    __syncthreads();
  }
  if (i < L) incl[i] = sm[threadIdx.x];
  if (threadIdx.x == 255) bsum[b] = sm[255];
}

__global__ void setup2_kernel(const int* __restrict__ cnt_e, int* __restrict__ incl_e,
                              int* __restrict__ bsum_e, int ebk, int E,
                              const int* __restrict__ cnt_n, int* __restrict__ incl_n,
                              int* __restrict__ bsum_n, int nbk, int N,
                              const float* __restrict__ nf, const float* __restrict__ taW,
                              const float* __restrict__ taB, float* __restrict__ atoms) {
  int b = blockIdx.x;
  if (b < ebk) scan_chunk(cnt_e, incl_e, bsum_e, E, b);
  else if (b < ebk + nbk) scan_chunk(cnt_n, incl_n, bsum_n, N, b - ebk);
  int i = b * 256 + threadIdx.x;
  if (i < N * 9) {
    int n = i / 9, d = i - n * 9;
    float acc = taB[d];
    for (int c = 0; c < 128; ++c) acc += nf[n * 128 + c] * taW[c * 9 + d];
    atoms[i] = sigm(acc);
  }
}

__global__ void scan_top2_kernel(int* __restrict__ bsum_e, int ne, int* __restrict__ bsum_n,
                                 int nn) {
  __shared__ int sm[1024];
  int* bs = blockIdx.x == 0 ? bsum_e : bsum_n;
  int nb = blockIdx.x == 0 ? ne : nn;
  int tid = threadIdx.x;
  int orig = tid < nb ? bs[tid] : 0;
  sm[tid] = orig;
  __syncthreads();
  for (int st = 1; st < 1024; st <<= 1) {
    int t = tid >= st ? sm[tid - st] : 0;
    __syncthreads();
    sm[tid] += t;
    __syncthreads();
  }
  if (tid < nb) bs[tid] = sm[tid] - orig;
}

__global__ void fin2_kernel(const int* __restrict__ cnt_e, const int* __restrict__ incl_e,
                            const int* __restrict__ bsum_e, int ebk, int* __restrict__ off_e,
                            int* __restrict__ cur_e, int E, const int* __restrict__ cnt_n,
                            const int* __restrict__ incl_n, const int* __restrict__ bsum_n,
                            int* __restrict__ off_n, int* __restrict__ cur_n, int N) {
  int b = blockIdx.x;
  if (b < ebk) {
    int i = b * 256 + threadIdx.x;
    if (i < E) {
      int o = incl_e[i] - cnt_e[i] + bsum_e[b];
      off_e[i] = o; cur_e[i] = o;
    }
  } else {
    int bb = b - ebk;
    int i = bb * 256 + threadIdx.x;
    if (i < N) {
      int o = incl_n[i] - cnt_n[i] + bsum_n[bb];
      off_n[i] = o; cur_n[i] = o;
    }
  }
}

// build: triplet precompute into CSR-sorted slots (bf16) + inverse dst-permutation
__global__ void build_kernel(const int* __restrict__ t_src, const int* __restrict__ t_dst,
                             const int* __restrict__ dst, const float* __restrict__ bvec,
                             const float* __restrict__ bdist, const float* __restrict__ rbf,
                             const float* __restrict__ cut3, int* __restrict__ cur_e,
                             ushort* __restrict__ stbp, int* __restrict__ sa, int T,
                             int* __restrict__ cur_n, int* __restrict__ invp, int E) {
  int t = blockIdx.x * 256 + threadIdx.x;
  if (t < T) {
    int i = t_src[t], j = t_dst[t];
    float ax = bvec[i * 3], ay = bvec[i * 3 + 1], az = bvec[i * 3 + 2];
    float bx = bvec[j * 3], by = bvec[j * 3 + 1], bz = bvec[j * 3 + 2];
    float ct = (ax * bx + ay * by + az * bz) / (bdist[i] * bdist[j]);
    float tw = cut3[i] * cut3[j];
    float sh[3];
    sh[0] = 0.28209479177387814f * tw;
    sh[1] = 0.4886025119029199f * ct * tw;
    sh[2] = 0.31539156525252005f * (3.0f * ct * ct - 1.0f) * tw;
    int pos = atomicAdd(&cur_e[i], 1);
#pragma unroll
    for (int l = 0; l < 3; ++l)
#pragma unroll
      for (int n = 0; n < 3; ++n)
        stbp[(size_t)pos * 9 + l * 3 + n] = (ushort)f2bf(rbf[j * 9 + l * 3 + n] * sh[l]);
    sa[pos] = dst[j];
  }
  if (t < E) {
    int pos = atomicAdd(&cur_n[dst[t]], 1);
    invp[t] = pos;
  }
}

// ---------------- weight packing (gmlp + tb + WT + eW + cnt-zero, one launch) -----------
__device__ void pack_one(const float* __restrict__ Wf, short* __restrict__ Wp, int K, int rr) {
  int per = 8 * (K / 32) * 64;
  int u = rr / per, r2 = rr - u * per;
  int lane = r2 & 63, tile = r2 >> 6;
  int kt = tile % (K / 32), nt = tile / (K / 32);
  int n = nt * 16 + (lane & 15);
  int k0 = kt * 32 + (lane >> 4) * 8;
  const float* s = Wf + (size_t)u * K * 128;
  bf16x8 v;
#pragma unroll
  for (int e = 0; e < 8; ++e) v[e] = f2bf(s[(size_t)(k0 + e) * 128 + n]);
  *(bf16x8*)(Wp + (size_t)u * K * 128 + (size_t)tile * 512 + lane * 8) = v;
}

__device__ void pack_pad9(const float* __restrict__ s, short* __restrict__ dp9, int l2) {
  int lane = l2 & 63, tile = l2 >> 6;
  int n = tile * 16 + (lane & 15);
  int k0 = (lane >> 4) * 8;
  bf16x8 v;
#pragma unroll
  for (int e = 0; e < 8; ++e)
    v[e] = (k0 + e < 9) ? f2bf(s[(size_t)(k0 + e) * 128 + n]) : (short)0;
  *(bf16x8*)(dp9 + tile * 512 + lane * 8) = v;
}

__global__ void pack_all_kernel(const float* __restrict__ W0, const float* __restrict__ G0,
                                const float* __restrict__ W1, const float* __restrict__ G1,
                                const float* __restrict__ W2, const float* __restrict__ G2,
                                const float* __restrict__ tbW, const float* __restrict__ tbG,
                                const float* __restrict__ WT, const float* __restrict__ eW,
                                short* __restrict__ pW0, short* __restrict__ pG0,
                                short* __restrict__ pW1, short* __restrict__ pG1,
                                short* __restrict__ pW2, short* __restrict__ pG2,
                                short* __restrict__ ptbW, short* __restrict__ ptbG,
                                short* __restrict__ pWT, short* __restrict__ peW,
                                int* __restrict__ cnt_all, int lenEN) {
  int idx = blockIdx.x * 256 + threadIdx.x;
  for (int z = idx; z < lenEN; z += gridDim.x * 256) cnt_all[z] = 0;
  const int t384 = 6 * 8 * 12 * 64, t128 = 6 * 8 * 4 * 64;
  if (idx < t384) { pack_one(W0, pW0, 384, idx); return; }
  if (idx < 2 * t384) { pack_one(G0, pG0, 384, idx - t384); return; }
  int j = idx - 2 * t384;
  if (j < t128) { pack_one(W1, pW1, 128, j); return; }
  if (j < 2 * t128) { pack_one(G1, pG1, 128, j - t128); return; }
  if (j < 3 * t128) { pack_one(W2, pW2, 128, j - 2 * t128); return; }
  if (j < 4 * t128) { pack_one(G2, pG2, 128, j - 3 * t128); return; }
  j -= 4 * t128;
  if (j < 3072) {  // tb weights: 3 k-blocks x {W,G} x 512
    int kb = j >> 10;
    int w2 = (j >> 9) & 1;
    int l2 = j & 511;
    const float* s = (w2 ? tbG : tbW) + (size_t)kb * 9 * 128;
    short* dp = (w2 ? ptbG : ptbW) + (size_t)kb * 4096;
    pack_pad9(s, dp, l2);
    return;
  }
  j -= 3072;
  if (j < 3072) {  // WT: 6 units x 512
    int u = j >> 9;
    pack_pad9(WT + (size_t)u * 9 * 128, pWT + (size_t)u * 4096, j & 511);
    return;
  }
  j -= 3072;
  if (j < 512) pack_pad9(eW, peW, j);  // edge-embedding weight
}

// ---------------- fused gated-MLP on MFMA ----------------
__device__ __forceinline__ f32x4 mfma16(bf16x8 a, bf16x8 b, f32x4 c) {
  return __builtin_amdgcn_mfma_f32_16x16x32_bf16(a, b, c, 0, 0, 0);
}

__device__ __forceinline__ void store_hg(short* hsb, short* gsb, int wave, int lane,
                                         const f32x4 (&aW)[2], const f32x4 (&aG)[2]) {
  const int lrow = lane & 15, lk = lane >> 4;
  const int colx = (wave * 16 + lrow) ^ (lk * 40);
#pragma unroll
  for (int mt = 0; mt < 2; ++mt)
#pragma unroll
    for (int rg = 0; rg < 4; ++rg) {
      int row = mt * 16 + lk * 4 + rg;
      hsb[row * HSS + colx] = f2bf1(silu(aW[mt][rg]));
      gsb[row * HSS + colx] = f2bf1(silu(aG[mt][rg]));
    }
}

__device__ __forceinline__ void layer128w(const short* hin, const short* gin,
                                          const short* __restrict__ pW,
                                          const short* __restrict__ pG,
                                          const float* __restrict__ Bh,
                                          const float* __restrict__ Bg, int wave, int lane,
                                          f32x4 (&aW)[2], f32x4 (&aG)[2]) {
  const int lrow = lane & 15, lk = lane >> 4;
  const int s0 = (lrow >> 2) & 3;
  float bw = Bh[wave * 16 + lrow], bg = Bg[wave * 16 + lrow];
  aW[0] = {bw, bw, bw, bw}; aW[1] = aW[0];
  aG[0] = {bg, bg, bg, bg}; aG[1] = aG[0];
#pragma unroll
  for (int kt = 0; kt < 4; ++kt) {
    int aoff = (kt * 32 + lk * 8) ^ (s0 * 40);
    bf16x8 ah0 = *(const bf16x8*)(hin + (size_t)lrow * HSS + aoff);
    bf16x8 ah1 = *(const bf16x8*)(hin + (size_t)(16 + lrow) * HSS + aoff);
    bf16x8 ag0 = *(const bf16x8*)(gin + (size_t)lrow * HSS + aoff);
    bf16x8 ag1 = *(const bf16x8*)(gin + (size_t)(16 + lrow) * HSS + aoff);
    bf16x8 bw8 = *(const bf16x8*)(pW + (size_t)(wave * 4 + kt) * 512 + lane * 8);
    bf16x8 bg8 = *(const bf16x8*)(pG + (size_t)(wave * 4 + kt) * 512 + lane * 8);
    aW[0] = mfma16(ah0, bw8, aW[0]);
    aW[1] = mfma16(ah1, bw8, aW[1]);
    aG[0] = mfma16(ag0, bg8, aG[0]);
    aG[1] = mfma16(ag1, bg8, aG[1]);
  }
}

__device__ __forceinline__ void run_chain(
    const short* xsb, short* hsb, short* gsb,
    const short* __restrict__ pW0, const short* __restrict__ pG0,
    const short* __restrict__ pW1, const short* __restrict__ pG1,
    const short* __restrict__ pW2, const short* __restrict__ pG2,
    const float* __restrict__ B0, const float* __restrict__ Gb0,
    const float* __restrict__ B1, const float* __restrict__ Gb1,
    const float* __restrict__ B2, const float* __restrict__ Gb2,
    int wave, int lane, f32x4 (&aW)[2], f32x4 (&aG)[2]) {
  const int lrow = lane & 15, lk = lane >> 4;
  const int s0 = (lrow >> 2) & 3;
  {
    float bw = B0[wave * 16 + lrow], bg = Gb0[wave * 16 + lrow];
    aW[0] = {bw, bw, bw, bw}; aW[1] = aW[0];
    aG[0] = {bg, bg, bg, bg}; aG[1] = aG[0];
  }
#pragma unroll
  for (int kt = 0; kt < 12; ++kt) {
    int al = kt * 32 + lk * 8;
    int aoff = (al < 256) ? al : (256 + ((al - 256) ^ (s0 << 4)));  // ef region swizzled
    bf16x8 a0 = *(const bf16x8*)(xsb + (size_t)lrow * XSS + aoff);
    bf16x8 a1 = *(const bf16x8*)(xsb + (size_t)(16 + lrow) * XSS + aoff);
    bf16x8 bw8 = *(const bf16x8*)(pW0 + (size_t)(wave * 12 + kt) * 512 + lane * 8);
    bf16x8 bg8 = *(const bf16x8*)(pG0 + (size_t)(wave * 12 + kt) * 512 + lane * 8);
    aW[0] = mfma16(a0, bw8, aW[0]);
    aW[1] = mfma16(a1, bw8, aW[1]);
    aG[0] = mfma16(a0, bg8, aG[0]);
    aG[1] = mfma16(a1, bg8, aG[1]);
  }
  store_hg(hsb, gsb, wave, lane, aW, aG);
  __syncthreads();
  layer128w(hsb, gsb, pW1, pG1, B1, Gb1, wave, lane, aW, aG);
  __syncthreads();
  store_hg(hsb, gsb, wave, lane, aW, aG);
  __syncthreads();
  layer128w(hsb, gsb, pW2, pG2, B2, Gb2, wave, lane, aW, aG);
}

template <int ISK0>
__global__ __launch_bounds__(512, 6) void gmlp_fused(
    const float* __restrict__ nf, float* __restrict__ ef, const float* __restrict__ rbf,
    const int* __restrict__ src, const int* __restrict__ dst,
    const ushort* __restrict__ stbp, const int* __restrict__ sa,
    const int* __restrict__ off_e, const int* __restrict__ cnt_e,
    const float* __restrict__ atoms, const int* __restrict__ invp,
    const short* __restrict__ ptbW, const short* __restrict__ ptbG,
    const short* __restrict__ peW, const float* __restrict__ eB,
    const short* __restrict__ pW0a, const short* __restrict__ pG0a,
    const short* __restrict__ pW1a, const short* __restrict__ pG1a,
    const short* __restrict__ pW2a, const short* __restrict__ pG2a,
    const float* __restrict__ B0a, const float* __restrict__ Gb0a,
    const float* __restrict__ B1a, const float* __restrict__ Gb1a,
    const float* __restrict__ B2a, const float* __restrict__ Gb2a,
    const short* __restrict__ pWTa,
    const short* __restrict__ pW0b, const short* __restrict__ pG0b,
    const short* __restrict__ pW1b, const short* __restrict__ pG1b,
    const short* __restrict__ pW2b, const short* __restrict__ pG2b,
    const float* __restrict__ B0b, const float* __restrict__ Gb0b,
    const float* __restrict__ B1b, const float* __restrict__ Gb1b,
    const float* __restrict__ B2b, const float* __restrict__ Gb2b,
    const short* __restrict__ pWTb,
    float* __restrict__ mbuf, int E, int writeEf) {
  __shared__ __align__(16) short xs[32][XSS];
  __shared__ __align__(16) short hs[32 * HSS];
  __shared__ __align__(16) short gs[32 * HSS];
  __shared__ __align__(16) short nbl[32][40];  // K=32-padded nb, bf16
  __shared__ __align__(16) short rbl[32][40];  // K=32-padded rbf, bf16
  __shared__ int invs[32];
  const int tid = threadIdx.x;
  const int e0 = blockIdx.x * TE;
  const int r = tid >> 4, q = tid & 15;
  int eg = e0 + r; if (eg >= E) eg = E - 1;

  // ---- fused nb_reduce -> bf16 nbl (zero-pad K 9..31) ----
  {
    float acc = 0.f;
    if (q < 9) {
      int o = off_e[eg], c = cnt_e[eg];
      for (int pp = o; pp < o + c; ++pp)
        acc += bf2f(stbp[(size_t)pp * 9 + q]) * atoms[(size_t)sa[pp] * 9 + q];
    }
    nbl[r][q] = (q < 9) ? f2bf1(acc) : (short)0;
    nbl[r][q + 16] = 0;
  }
  // ---- gather nf segments as bf16; rbf -> rbl bf16 ----
  {
    const float* sp0 = nf + (size_t)src[eg] * 128;
    const float* sp1 = nf + (size_t)dst[eg] * 128;
#pragma unroll
    for (int seg = 0; seg < 2; ++seg) {
      const float* sp = seg == 0 ? sp0 : sp1;
      float4 f0 = *(const float4*)(sp + q * 8);
      float4 f1 = *(const float4*)(sp + q * 8 + 4);
      u32x4 v = {cvt2(f0.x, f0.y), cvt2(f0.z, f0.w), cvt2(f1.x, f1.y), cvt2(f1.z, f1.w)};
      *(u32x4*)&xs[r][seg * 128 + q * 8] = v;
    }
    for (int idx = tid; idx < 32 * 32; idx += 512) {
      int rr = idx >> 5, d = idx & 31;
      int ee = e0 + rr; if (ee >= E) ee = E - 1;
      rbl[rr][d] = (d < 9) ? f2bf1(rbf[ee * 9 + d]) : (short)0;
    }
    if (tid < 32) {
      int ee = e0 + tid; if (ee >= E) ee = E - 1;
      invs[tid] = invp[ee];
    }
  }
  __syncthreads();

  const int wave = tid >> 6;
  const int lane = tid & 63;
  const int lrow = lane & 15, lk = lane >> 4;
  const int col = wave * 16 + lrow;
  const int cs = 256 + (col ^ (lk << 4));
  f32x4 aW[2], aG[2];
  float efb[2][4];  // ef + tb_update base, carried in registers through chain 0

  // ---- tb_update via MFMA (+ compile-time edge_emb fusion at k=0) ----
  {
    bf16x8 ta0 = *(const bf16x8*)&nbl[lrow][lk * 8];
    bf16x8 ta1 = *(const bf16x8*)&nbl[16 + lrow][lk * 8];
    bf16x8 tbw = *(const bf16x8*)(ptbW + wave * 512 + lane * 8);
    bf16x8 tbg = *(const bf16x8*)(ptbG + wave * 512 + lane * 8);
    f32x4 z = {0.f, 0.f, 0.f, 0.f};
    f32x4 tW0 = mfma16(ta0, tbw, z), tW1 = mfma16(ta1, tbw, z);
    f32x4 tG0 = mfma16(ta0, tbg, z), tG1 = mfma16(ta1, tbg, z);
    if (ISK0) {  // ef = silu(rbf @ eW + eB), computed in-place
      bf16x8 ra0 = *(const bf16x8*)&rbl[lrow][lk * 8];
      bf16x8 ra1 = *(const bf16x8*)&rbl[16 + lrow][lk * 8];
      bf16x8 ew8 = *(const bf16x8*)(peW + wave * 512 + lane * 8);
      float ebv = eB[col];
      f32x4 ec = {ebv, ebv, ebv, ebv};
      f32x4 e0v = mfma16(ra0, ew8, ec);
      f32x4 e1v = mfma16(ra1, ew8, ec);
#pragma unroll
      for (int mt = 0; mt < 2; ++mt)
#pragma unroll
        for (int rg = 0; rg < 4; ++rg) {
          int row = mt * 16 + lk * 4 + rg;
          float tw = mt == 0 ? tW0[rg] : tW1[rg];
          float tg = mt == 0 ? tG0[rg] : tG1[rg];
          float base = silu(mt == 0 ? e0v[rg] : e1v[rg]) + tw * sig2(tw, tg);
          efb[mt][rg] = base;
          xs[row][cs] = f2bf1(base);
        }
    } else {
#pragma unroll
      for (int mt = 0; mt < 2; ++mt)
#pragma unroll
        for (int rg = 0; rg < 4; ++rg) {
          int row = mt * 16 + lk * 4 + rg;
          int ec2 = e0 + row; if (ec2 >= E) ec2 = E - 1;
          float tw = mt == 0 ? tW0[rg] : tW1[rg];
          float tg = mt == 0 ? tG0[rg] : tG1[rg];
          float base = ef[(size_t)ec2 * 128 + col] + tw * sig2(tw, tg);
          efb[mt][rg] = base;
          xs[row][cs] = f2bf1(base);
        }
    }
  }
  __syncthreads();

  // ---- chain 0: edge update ----
  run_chain(&xs[0][0], hs, gs, pW0a, pG0a, pW1a, pG1a, pW2a, pG2a,
            B0a, Gb0a, B1a, Gb1a, B2a, Gb2a, wave, lane, aW, aG);
  {
    bf16x8 ra0 = *(const bf16x8*)&rbl[lrow][lk * 8];
    bf16x8 ra1 = *(const bf16x8*)&rbl[16 + lrow][lk * 8];
    bf16x8 wtb = *(const bf16x8*)(pWTa + wave * 512 + lane * 8);
    f32x4 z = {0.f, 0.f, 0.f, 0.f};
    f32x4 wv0 = mfma16(ra0, wtb, z), wv1 = mfma16(ra1, wtb, z);
#pragma unroll
    for (int mt = 0; mt < 2; ++mt)
#pragma unroll
      for (int rg = 0; rg < 4; ++rg) {
        int row = mt * 16 + lk * 4 + rg;
        int e = e0 + row;
        float wv = mt == 0 ? wv0[rg] : wv1[rg];
        float a = aW[mt][rg], g = aG[mt][rg];
        float v = a * sig2(a, g) * wv;
        float nv = efb[mt][rg] + v;
        if (e < E && writeEf) ef[(size_t)e * 128 + col] = nv;
        xs[row][cs] = f2bf1(nv);
      }
  }
  __syncthreads();

  // ---- chain 1: node update ----
  run_chain(&xs[0][0], hs, gs, pW0b, pG0b, pW1b, pG1b, pW2b, pG2b,
            B0b, Gb0b, B1b, Gb1b, B2b, Gb2b, wave, lane, aW, aG);
  {
    bf16x8 ra0 = *(const bf16x8*)&rbl[lrow][lk * 8];
    bf16x8 ra1 = *(const bf16x8*)&rbl[16 + lrow][lk * 8];
    bf16x8 wtb = *(const bf16x8*)(pWTb + wave * 512 + lane * 8);
    f32x4 z = {0.f, 0.f, 0.f, 0.f};
    f32x4 wv0 = mfma16(ra0, wtb, z), wv1 = mfma16(ra1, wtb, z);
#pragma unroll
    for (int mt = 0; mt < 2; ++mt)
#pragma unroll
      for (int rg = 0; rg < 4; ++rg) {
        int row = mt * 16 + lk * 4 + rg;
        int e = e0 + row;
        float wv = mt == 0 ? wv0[rg] : wv1[rg];
        float a = aW[mt][rg], g = aG[mt][rg];
        float v = a * sig2(a, g) * wv;
        if (e < E) mbuf[(size_t)invs[row] * 128 + col] = v;  // dst-sorted position
      }
  }
}

// ---- node gather (sequential, dst-sorted mbuf) + parallel fused atoms ----
__global__ void node_gather_kernel(float* __restrict__ nf, const float* __restrict__ mbuf,
                                   const int* __restrict__ off_n, const int* __restrict__ cnt_n,
                                   const float* __restrict__ taW, const float* __restrict__ taB,
                                   float* __restrict__ atoms, int N, int doAtoms) {
  __shared__ float red[2][9][128];
  int half = threadIdx.x >> 7, c = threadIdx.x & 127;
  int n = blockIdx.x * 2 + half;
  float v = 0.f;
  if (n < N) {
    int o = off_n[n], cnt = cnt_n[n];
    float acc = 0.f;
    for (int p = 0; p < cnt; ++p) acc += mbuf[(size_t)(o + p) * 128 + c];
    v = nf[(size_t)n * 128 + c] + acc;
    nf[(size_t)n * 128 + c] = v;
  }
  if (doAtoms) {
#pragma unroll
    for (int d = 0; d < 9; ++d) red[half][d][c] = (n < N) ? v * taW[c * 9 + d] : 0.f;
    for (int s = 64; s >= 1; s >>= 1) {
      __syncthreads();
      for (int idx = threadIdx.x; idx < 2 * 9 * s; idx += 256) {
        int h = idx / (9 * s), rem = idx - h * 9 * s;
        int d = rem / s, j = rem - d * s;
        red[h][d][j] += red[h][d][j + s];
      }
    }
    __syncthreads();
    if (threadIdx.x < 18) {
      int h = threadIdx.x / 9, d = threadIdx.x - h * 9;
      int nn = blockIdx.x * 2 + h;
      if (nn < N) atoms[nn * 9 + d] = sigm(red[h][d][0] + taB[d]);
    }
  }
}

// ---------------- readout ----------------
__global__ void mean_kernel(const float* __restrict__ nf, float* __restrict__ partial, int N) {
  __shared__ float sm[256];
  int n0 = blockIdx.x * 256;
  int col = threadIdx.x & 127, half = threadIdx.x >> 7;
  int nend = n0 + 256 < N ? n0 + 256 : N;
  float s = 0.f;
  for (int n = n0 + half; n < nend; n += 2) s += nf[n * 128 + col];
  sm[threadIdx.x] = s;
  __syncthreads();
  if (threadIdx.x < 128)
    partial[blockIdx.x * 128 + threadIdx.x] = sm[threadIdx.x] + sm[threadIdx.x + 128];
}

__global__ void final_kernel(const float* __restrict__ partial, int nchunks, float Nf,
                             const float* __restrict__ fW0, const float* __restrict__ fb0,
                             const float* __restrict__ fW1, const float* __restrict__ fb1,
                             const float* __restrict__ fW2, const float* __restrict__ fb2,
                             float* __restrict__ out) {
  __shared__ float v[128], h[128], red[128];
  int tid = threadIdx.x;  // 128 threads
  float s = 0.f;
  for (int b = 0; b < nchunks; ++b) s += partial[b * 128 + tid];
  v[tid] = s / Nf;
  __syncthreads();
  float acc = fb0[tid];
  for (int c = 0; c < 128; ++c) acc += v[c] * fW0[c * 128 + tid];
  h[tid] = silu(acc);
  __syncthreads();
  acc = fb1[tid];
  for (int c = 0; c < 128; ++c) acc += h[c] * fW1[c * 128 + tid];
  __syncthreads();
  v[tid] = silu(acc);
  __syncthreads();
  red[tid] = v[tid] * fW2[tid];
  __syncthreads();
  for (int st = 64; st > 0; st >>= 1) {
    if (tid < st) red[tid] += red[tid + st];
    __syncthreads();
  }
  if (tid == 0) out[0] = red[0] + fb2[0];
}

// ---------------- launch ----------------
extern "C" void kernel_launch(void* const* d_in, const int* in_sizes, int n_in,
                              void* d_out, int out_size, void* d_ws, size_t ws_size,
                              hipStream_t stream) {
  const float* pos = (const float*)d_in[0];
  const int* node_type = (const int*)d_in[1];
  const int* src = (const int*)d_in[2];
  const int* dst = (const int*)d_in[3];
  const int* t_src = (const int*)d_in[4];
  const int* t_dst = (const int*)d_in[5];
  const float* emb = (const float*)d_in[6];
  const float* eW = (const float*)d_in[7];
  const float* eB = (const float*)d_in[8];
  const float* taW = (const float*)d_in[9];
  const float* taB = (const float*)d_in[10];
  const float* tbW = (const float*)d_in[11];
  const float* tbG = (const float*)d_in[12];
  const float* W0 = (const float*)d_in[13]; const float* B0 = (const float*)d_in[14];
  const float* W1 = (const float*)d_in[15]; const float* B1 = (const float*)d_in[16];
  const float* W2 = (const float*)d_in[17]; const float* B2 = (const float*)d_in[18];
  const float* G0 = (const float*)d_in[19]; const float* Gb0 = (const float*)d_in[20];
  const float* G1 = (const float*)d_in[21]; const float* Gb1 = (const float*)d_in[22];
  const float* G2 = (const float*)d_in[23]; const float* Gb2 = (const float*)d_in[24];
  const float* WT = (const float*)d_in[25];
  const float* fW0 = (const float*)d_in[26]; const float* fb0 = (const float*)d_in[27];
  const float* fW1 = (const float*)d_in[28]; const float* fb1 = (const float*)d_in[29];
  const float* fW2 = (const float*)d_in[30]; const float* fb2 = (const float*)d_in[31];

  const int N = in_sizes[1];
  const int E = in_sizes[2];
  const int T = in_sizes[4];

  char* p = (char*)d_ws;
  auto alloc = [&](size_t bytes) -> char* {
    char* r = p;
    p += (bytes + 255) & ~(size_t)255;
    return r;
  };
  float*  nf    = (float*)alloc((size_t)N * 128 * 4);
  float*  ef    = (float*)alloc((size_t)E * 128 * 4);
  float*  mbuf  = (float*)alloc((size_t)E * 128 * 4);
  float*  rbf   = (float*)alloc((size_t)E * 9 * 4);
  float*  bvec  = (float*)alloc((size_t)E * 3 * 4);
  float*  bdist = (float*)alloc((size_t)E * 4);
  float*  cut3  = (float*)alloc((size_t)E * 4);
  ushort* stbp  = (ushort*)alloc((size_t)T * 9 * 2);
  int*    sa    = (int*)alloc((size_t)T * 4);
  float*  atoms = (float*)alloc((size_t)N * 9 * 4);
  float*  part  = (float*)alloc((size_t)64 * 128 * 4);
  int* cnt_all = (int*)alloc((size_t)(E + N) * 4);
  int* cnt_e = cnt_all, *cnt_n = cnt_all + E;
  int* incl_e = (int*)alloc((size_t)E * 4);
  int* incl_n = (int*)alloc((size_t)N * 4);
  int* off_e  = (int*)alloc((size_t)E * 4);
  int* off_n  = (int*)alloc((size_t)N * 4);
  int* cur_e  = (int*)alloc((size_t)E * 4);
  int* cur_n  = (int*)alloc((size_t)N * 4);
  int* invp   = (int*)alloc((size_t)E * 4);
  int* bsum_e = (int*)alloc((size_t)1024 * 4);
  int* bsum_n = (int*)alloc((size_t)1024 * 4);
  short* pW0s = (short*)alloc((size_t)6 * 384 * 128 * 2);
  short* pG0s = (short*)alloc((size_t)6 * 384 * 128 * 2);
  short* pW1s = (short*)alloc((size_t)6 * 128 * 128 * 2);
  short* pG1s = (short*)alloc((size_t)6 * 128 * 128 * 2);
  short* pW2s = (short*)alloc((size_t)6 * 128 * 128 * 2);
  short* pG2s = (short*)alloc((size_t)6 * 128 * 128 * 2);
  short* ptbWs = (short*)alloc((size_t)3 * 4096 * 2);
  short* ptbGs = (short*)alloc((size_t)3 * 4096 * 2);
  short* pWTs  = (short*)alloc((size_t)6 * 4096 * 2);
  short* peWs  = (short*)alloc((size_t)4096 * 2);
  (void)ws_size; (void)n_in; (void)out_size;

  const int ebk = (E + 255) / 256, nbk = (N + 255) / 256;

  pack_all_kernel<<<506, 256, 0, stream>>>(W0, G0, W1, G1, W2, G2, tbW, tbG, WT, eW,
                                           pW0s, pG0s, pW1s, pG1s, pW2s, pG2s,
                                           ptbWs, ptbGs, pWTs, peWs, cnt_all, E + N);
  {
    int g1 = N * 128; if (E > g1) g1 = E; if (T > g1) g1 = T;
    setup1_kernel<<<(g1 + 255) / 256, 256, 0, stream>>>(
        node_type, emb, nf, N, pos, src, dst, bvec, bdist, rbf, cut3, E, t_src, cnt_e, cnt_n, T);
  }
  {
    int g2 = (ebk + nbk) * 256; if (N * 9 > g2) g2 = N * 9;
    setup2_kernel<<<(g2 + 255) / 256, 256, 0, stream>>>(
        cnt_e, incl_e, bsum_e, ebk, E, cnt_n, incl_n, bsum_n, nbk, N, nf, taW, taB, atoms);
  }
  scan_top2_kernel<<<2, 1024, 0, stream>>>(bsum_e, ebk, bsum_n, nbk);
  fin2_kernel<<<ebk + nbk, 256, 0, stream>>>(cnt_e, incl_e, bsum_e, ebk, off_e, cur_e, E,
                                             cnt_n, incl_n, bsum_n, off_n, cur_n, N);
  {
    int g3 = T > E ? T : E;
    build_kernel<<<(g3 + 255) / 256, 256, 0, stream>>>(t_src, t_dst, dst, bvec, bdist, rbf,
                                                       cut3, cur_e, stbp, sa, T, cur_n, invp, E);
  }

  const int gblocks = (E + TE - 1) / TE;
  for (int k = 0; k < 3; ++k) {
    size_t u0 = (size_t)(k * 2 + 0), u1 = u0 + 1;
#define GMLP_ARGS                                                                          \
    nf, ef, rbf, src, dst, stbp, sa, off_e, cnt_e, atoms, invp,                            \
    ptbWs + (size_t)k * 4096, ptbGs + (size_t)k * 4096, peWs, eB,                          \
    pW0s + u0 * 384 * 128, pG0s + u0 * 384 * 128, pW1s + u0 * 128 * 128,                   \
    pG1s + u0 * 128 * 128, pW2s + u0 * 128 * 128, pG2s + u0 * 128 * 128,                   \
    B0 + u0 * 128, Gb0 + u0 * 128, B1 + u0 * 128, Gb1 + u0 * 128, B2 + u0 * 128,           \
    Gb2 + u0 * 128, pWTs + u0 * 4096,                                                      \
    pW0s + u1 * 384 * 128, pG0s + u1 * 384 * 128, pW1s + u1 * 128 * 128,                   \
    pG1s + u1 * 128 * 128, pW2s + u1 * 128 * 128, pG2s + u1 * 128 * 128,                   \
    B0 + u1 * 128, Gb0 + u1 * 128, B1 + u1 * 128, Gb1 + u1 * 128, B2 + u1 * 128,           \
    Gb2 + u1 * 128, pWTs + u1 * 4096,                                                      \
    mbuf, E, k < 2 ? 1 : 0
    if (k == 0) gmlp_fused<1><<<gblocks, 512, 0, stream>>>(GMLP_ARGS);
    else        gmlp_fused<0><<<gblocks, 512, 0, stream>>>(GMLP_ARGS);
#undef GMLP_ARGS
    int nk = k < 2 ? k + 1 : 0;
    node_gather_kernel<<<(N + 1) / 2, 256, 0, stream>>>(
        nf, mbuf, off_n, cnt_n, taW + (size_t)nk * 128 * 9, taB + (size_t)nk * 9,
        atoms, N, k < 2 ? 1 : 0);
  }

  int nchunks = (N + 255) / 256;
  mean_kernel<<<nchunks, 256, 0, stream>>>(nf, part, N);
  final_kernel<<<1, 128, 0, stream>>>(part, nchunks, (float)N, fW0, fb0, fW1, fb1, fW2, fb2,
                                      (float*)d_out);
}

// Round 19
// 465.229 us; speedup vs baseline: 1.1061x; 1.0142x over previous
//
#include <hip/hip_runtime.h>
#include <stdint.h>

typedef __attribute__((ext_vector_type(8))) short bf16x8;
typedef __attribute__((ext_vector_type(4))) float f32x4;
typedef __attribute__((ext_vector_type(4))) uint32_t u32x4;
typedef unsigned short ushort;

#define XSS 392   // xs row stride (shorts)
#define HSS 144   // hs/gs row stride (shorts); swizzle mask = ((row>>2)&3)*40
#define TE 32

// ---------------- helpers ----------------
__device__ __forceinline__ float sigm(float x) { return __fdividef(1.0f, 1.0f + __expf(-x)); }
__device__ __forceinline__ float silu(float x) { return __fdividef(x, 1.0f + __expf(-x)); }
// sigm(a)*sigm(g) with a single rcp; overflow -> 0 gives correct asymptote
__device__ __forceinline__ float sig2(float a, float g) {
  return __fdividef(1.0f, (1.0f + __expf(-a)) * (1.0f + __expf(-g)));
}
__device__ __forceinline__ short f2bf(float f) {  // RNE f32->bf16 (pack path)
  uint32_t u = __float_as_uint(f);
  u = (u + 0x7fffu + ((u >> 16) & 1u)) >> 16;
  return (short)u;
}
__device__ __forceinline__ float bf2f(ushort u) { return __uint_as_float(((uint32_t)u) << 16); }
__device__ __forceinline__ uint32_t cvt2(float lo, float hi) {
  uint32_t d;
  asm("v_cvt_pk_bf16_f32 %0, %1, %2" : "=v"(d) : "v"(lo), "v"(hi));
  return d;
}
__device__ __forceinline__ short f2bf1(float f) { return (short)cvt2(f, f); }

// fast hardware trig (args ≤ ~30 rad; ~1e-6 abs err — fine at bf16 tolerance)
__device__ __forceinline__ float jl_eval(int l, float x) {
  float s, c;
  __sincosf(x, &s, &c);
  float ix = 1.0f / x, ix2 = ix * ix;
  if (l == 0) return s * ix;
  if (l == 1) return s * ix2 - c * ix;
  if (l == 2) return (3.0f * ix2 * ix - ix) * s - 3.0f * ix2 * c;
  return (15.0f * ix2 * ix2 - 6.0f * ix2) * s - (15.0f * ix2 * ix - ix) * c;
}

// ---------------- setup1: node_init + edge_geom + CSR counts ----------------
__global__ void setup1_kernel(const int* __restrict__ ntb, const float* __restrict__ emb,
                              float* __restrict__ nf, int N,
                              const float* __restrict__ pos, const int* __restrict__ src,
                              const int* __restrict__ dst, float* __restrict__ bvec,
                              float* __restrict__ bdist, float* __restrict__ rbf,
                              float* __restrict__ cut3, int E,
                              const int* __restrict__ t_src, int* __restrict__ cnt_e,
                              int* __restrict__ cnt_n, int T) {
  int i = blockIdx.x * 256 + threadIdx.x;
  if (i < N * 128) {
    int n = i >> 7, c = i & 127;
    nf[i] = emb[ntb[n] * 128 + c];
  }
  if (i < E) {
    int s = src[i], d = dst[i];
    float dx = pos[d * 3 + 0] - pos[s * 3 + 0];
    float dy = pos[d * 3 + 1] - pos[s * 3 + 1];
    float dz = pos[d * 3 + 2] - pos[s * 3 + 2];
    float r = sqrtf(dx * dx + dy * dy + dz * dz + 1e-12f);
    bvec[i * 3 + 0] = dx; bvec[i * 3 + 1] = dy; bvec[i * 3 + 2] = dz;
    bdist[i] = r;
    const float roots[3][3] = {
        {3.141592653589793f, 6.283185307179586f, 9.42477796076938f},
        {4.493409457909064f, 7.725251836937707f, 10.904121659428899f},
        {5.763459196894550f, 9.095011330476355f, 12.322940970566582f}};
#pragma unroll
    for (int l = 0; l < 3; ++l) {
#pragma unroll
      for (int n = 0; n < 3; ++n) {
        float root = roots[l][n];
        float x = r * (root * 0.2f);
        float norm;
        if (l == 0) norm = 1.0f / root;
        else if (l == 1) norm = 1.0f / sqrtf(1.0f + root * root);
        else {
          float t = 3.0f * root / (3.0f - root * root);
          norm = fabsf(t - root) / (root * root * sqrtf(1.0f + t * t));
        }
        rbf[i * 9 + l * 3 + n] = jl_eval(l, x) * (0.12649110640673518f / norm);
      }
    }
    float xx = r * 0.25f;
    float x3 = xx * xx * xx;
    cut3[i] = 1.0f - 6.0f * x3 * xx * xx + 15.0f * x3 * xx - 10.0f * x3;
    atomicAdd(&cnt_n[d], 1);
  }
  if (i < T) atomicAdd(&cnt_e[t_src[i]], 1);
}

// ---------------- setup2: block scans + parallel atoms(k=0) ----------------
__device__ void scan_chunk(const int* __restrict__ in, int* __restrict__ incl,
                           int* __restrict__ bsum, int L, int b) {
  __shared__ int sm[256];
  int i = b * 256 + threadIdx.x;
  int v = i < L ? in[i] : 0;
  sm[threadIdx.x] = v;
  __syncthreads();
  for (int st = 1; st < 256; st <<= 1) {
    int t = threadIdx.x >= st ? sm[threadIdx.x - st] : 0;
    __syncthreads();
    sm[threadIdx.x] += t;
    __syncthreads();
  }
  if (i < L) incl[i] = sm[threadIdx.x];
  if (threadIdx.x == 255) bsum[b] = sm[255];
}

__global__ void setup2_kernel(const int* __restrict__ cnt_e, int* __restrict__ incl_e,
                              int* __restrict__ bsum_e, int ebk, int E,
                              const int* __restrict__ cnt_n, int* __restrict__ incl_n,
                              int* __restrict__ bsum_n, int nbk, int N,
                              const float* __restrict__ nf, const float* __restrict__ taW,
                              const float* __restrict__ taB, float* __restrict__ atoms) {
  int b = blockIdx.x;
  if (b < ebk) scan_chunk(cnt_e, incl_e, bsum_e, E, b);
  else if (b < ebk + nbk) scan_chunk(cnt_n, incl_n, bsum_n, N, b - ebk);
  // parallel atoms: 2 nodes per block, 9 partials/lane + tree reduce
  __shared__ float red[2][9][128];
  int half = threadIdx.x >> 7, c = threadIdx.x & 127;
  int n = b * 2 + half;
  float v = (n < N) ? nf[(size_t)n * 128 + c] : 0.f;
#pragma unroll
  for (int d = 0; d < 9; ++d) red[half][d][c] = v * taW[c * 9 + d];
  for (int s = 64; s >= 1; s >>= 1) {
    __syncthreads();
    for (int idx = threadIdx.x; idx < 2 * 9 * s; idx += 256) {
      int h = idx / (9 * s), rem = idx - h * 9 * s;
      int d = rem / s, j = rem - d * s;
      red[h][d][j] += red[h][d][j + s];
    }
  }
  __syncthreads();
  if (threadIdx.x < 18) {
    int h = threadIdx.x / 9, d = threadIdx.x - h * 9;
    int nn = b * 2 + h;
    if (nn < N) atoms[nn * 9 + d] = sigm(red[h][d][0] + taB[d]);
  }
}

// fin2: per-block exclusive prefix of raw bsum (ebk,nbk < 256) + offsets (absorbs scan_top2)
__global__ void fin2_kernel(const int* __restrict__ cnt_e, const int* __restrict__ incl_e,
                            const int* __restrict__ bsum_e, int ebk, int* __restrict__ off_e,
                            int* __restrict__ cur_e, int E, const int* __restrict__ cnt_n,
                            const int* __restrict__ incl_n, const int* __restrict__ bsum_n,
                            int* __restrict__ off_n, int* __restrict__ cur_n, int N) {
  __shared__ int sm[256];
  int b = blockIdx.x, tid = threadIdx.x;
  const int* bs = (b < ebk) ? bsum_e : bsum_n;
  int bb = (b < ebk) ? b : b - ebk;
  sm[tid] = (tid < bb) ? bs[tid] : 0;
  __syncthreads();
  for (int s = 128; s >= 1; s >>= 1) {
    if (tid < s) sm[tid] += sm[tid + s];
    __syncthreads();
  }
  int bex = sm[0];
  if (b < ebk) {
    int i = b * 256 + tid;
    if (i < E) {
      int o = incl_e[i] - cnt_e[i] + bex;
      off_e[i] = o; cur_e[i] = o;
    }
  } else {
    int i = bb * 256 + tid;
    if (i < N) {
      int o = incl_n[i] - cnt_n[i] + bex;
      off_n[i] = o; cur_n[i] = o;
    }
  }
}

// build: triplet precompute into CSR-sorted slots (bf16) + inverse dst-permutation
__global__ void build_kernel(const int* __restrict__ t_src, const int* __restrict__ t_dst,
                             const int* __restrict__ dst, const float* __restrict__ bvec,
                             const float* __restrict__ bdist, const float* __restrict__ rbf,
                             const float* __restrict__ cut3, int* __restrict__ cur_e,
                             ushort* __restrict__ stbp, int* __restrict__ sa, int T,
                             int* __restrict__ cur_n, int* __restrict__ invp, int E) {
  int t = blockIdx.x * 256 + threadIdx.x;
  if (t < T) {
    int i = t_src[t], j = t_dst[t];
    float ax = bvec[i * 3], ay = bvec[i * 3 + 1], az = bvec[i * 3 + 2];
    float bx = bvec[j * 3], by = bvec[j * 3 + 1], bz = bvec[j * 3 + 2];
    float ct = (ax * bx + ay * by + az * bz) / (bdist[i] * bdist[j]);
    float tw = cut3[i] * cut3[j];
    float sh[3];
    sh[0] = 0.28209479177387814f * tw;
    sh[1] = 0.4886025119029199f * ct * tw;
    sh[2] = 0.31539156525252005f * (3.0f * ct * ct - 1.0f) * tw;
    int pos = atomicAdd(&cur_e[i], 1);
#pragma unroll
    for (int l = 0; l < 3; ++l)
#pragma unroll
      for (int n = 0; n < 3; ++n)
        stbp[(size_t)pos * 9 + l * 3 + n] = (ushort)f2bf(rbf[j * 9 + l * 3 + n] * sh[l]);
    sa[pos] = dst[j];
  }
  if (t < E) {
    int pos = atomicAdd(&cur_n[dst[t]], 1);
    invp[t] = pos;
  }
}

// ---------------- weight packing (gmlp + tb + WT + eW + cnt-zero, one launch) -----------
__device__ void pack_one(const float* __restrict__ Wf, short* __restrict__ Wp, int K, int rr) {
  int per = 8 * (K / 32) * 64;
  int u = rr / per, r2 = rr - u * per;
  int lane = r2 & 63, tile = r2 >> 6;
  int kt = tile % (K / 32), nt = tile / (K / 32);
  int n = nt * 16 + (lane & 15);
  int k0 = kt * 32 + (lane >> 4) * 8;
  const float* s = Wf + (size_t)u * K * 128;
  bf16x8 v;
#pragma unroll
  for (int e = 0; e < 8; ++e) v[e] = f2bf(s[(size_t)(k0 + e) * 128 + n]);
  *(bf16x8*)(Wp + (size_t)u * K * 128 + (size_t)tile * 512 + lane * 8) = v;
}

__device__ void pack_pad9(const float* __restrict__ s, short* __restrict__ dp9, int l2) {
  int lane = l2 & 63, tile = l2 >> 6;
  int n = tile * 16 + (lane & 15);
  int k0 = (lane >> 4) * 8;
  bf16x8 v;
#pragma unroll
  for (int e = 0; e < 8; ++e)
    v[e] = (k0 + e < 9) ? f2bf(s[(size_t)(k0 + e) * 128 + n]) : (short)0;
  *(bf16x8*)(dp9 + tile * 512 + lane * 8) = v;
}

__global__ void pack_all_kernel(const float* __restrict__ W0, const float* __restrict__ G0,
                                const float* __restrict__ W1, const float* __restrict__ G1,
                                const float* __restrict__ W2, const float* __restrict__ G2,
                                const float* __restrict__ tbW, const float* __restrict__ tbG,
                                const float* __restrict__ WT, const float* __restrict__ eW,
                                short* __restrict__ pW0, short* __restrict__ pG0,
                                short* __restrict__ pW1, short* __restrict__ pG1,
                                short* __restrict__ pW2, short* __restrict__ pG2,
                                short* __restrict__ ptbW, short* __restrict__ ptbG,
                                short* __restrict__ pWT, short* __restrict__ peW,
                                int* __restrict__ cnt_all, int lenEN) {
  int idx = blockIdx.x * 256 + threadIdx.x;
  for (int z = idx; z < lenEN; z += gridDim.x * 256) cnt_all[z] = 0;
  const int t384 = 6 * 8 * 12 * 64, t128 = 6 * 8 * 4 * 64;
  if (idx < t384) { pack_one(W0, pW0, 384, idx); return; }
  if (idx < 2 * t384) { pack_one(G0, pG0, 384, idx - t384); return; }
  int j = idx - 2 * t384;
  if (j < t128) { pack_one(W1, pW1, 128, j); return; }
  if (j < 2 * t128) { pack_one(G1, pG1, 128, j - t128); return; }
  if (j < 3 * t128) { pack_one(W2, pW2, 128, j - 2 * t128); return; }
  if (j < 4 * t128) { pack_one(G2, pG2, 128, j - 3 * t128); return; }
  j -= 4 * t128;
  if (j < 3072) {  // tb weights: 3 k-blocks x {W,G} x 512
    int kb = j >> 10;
    int w2 = (j >> 9) & 1;
    int l2 = j & 511;
    const float* s = (w2 ? tbG : tbW) + (size_t)kb * 9 * 128;
    short* dp = (w2 ? ptbG : ptbW) + (size_t)kb * 4096;
    pack_pad9(s, dp, l2);
    return;
  }
  j -= 3072;
  if (j < 3072) {  // WT: 6 units x 512
    int u = j >> 9;
    pack_pad9(WT + (size_t)u * 9 * 128, pWT + (size_t)u * 4096, j & 511);
    return;
  }
  j -= 3072;
  if (j < 512) pack_pad9(eW, peW, j);  // edge-embedding weight
}

// ---------------- fused gated-MLP on MFMA ----------------
__device__ __forceinline__ f32x4 mfma16(bf16x8 a, bf16x8 b, f32x4 c) {
  return __builtin_amdgcn_mfma_f32_16x16x32_bf16(a, b, c, 0, 0, 0);
}

__device__ __forceinline__ void store_hg(short* hsb, short* gsb, int wave, int lane,
                                         const f32x4 (&aW)[2], const f32x4 (&aG)[2]) {
  const int lrow = lane & 15, lk = lane >> 4;
  const int colx = (wave * 16 + lrow) ^ (lk * 40);
#pragma unroll
  for (int mt = 0; mt < 2; ++mt)
#pragma unroll
    for (int rg = 0; rg < 4; ++rg) {
      int row = mt * 16 + lk * 4 + rg;
      hsb[row * HSS + colx] = f2bf1(silu(aW[mt][rg]));
      gsb[row * HSS + colx] = f2bf1(silu(aG[mt][rg]));
    }
}

__device__ __forceinline__ void layer128w(const short* hin, const short* gin,
                                          const short* __restrict__ pW,
                                          const short* __restrict__ pG,
                                          const float* __restrict__ Bh,
                                          const float* __restrict__ Bg, int wave, int lane,
                                          f32x4 (&aW)[2], f32x4 (&aG)[2]) {
  const int lrow = lane & 15, lk = lane >> 4;
  const int s0 = (lrow >> 2) & 3;
  float bw = Bh[wave * 16 + lrow], bg = Bg[wave * 16 + lrow];
  aW[0] = {bw, bw, bw, bw}; aW[1] = aW[0];
  aG[0] = {bg, bg, bg, bg}; aG[1] = aG[0];
#pragma unroll
  for (int kt = 0; kt < 4; ++kt) {
    int aoff = (kt * 32 + lk * 8) ^ (s0 * 40);
    bf16x8 ah0 = *(const bf16x8*)(hin + (size_t)lrow * HSS + aoff);
    bf16x8 ah1 = *(const bf16x8*)(hin + (size_t)(16 + lrow) * HSS + aoff);
    bf16x8 ag0 = *(const bf16x8*)(gin + (size_t)lrow * HSS + aoff);
    bf16x8 ag1 = *(const bf16x8*)(gin + (size_t)(16 + lrow) * HSS + aoff);
    bf16x8 bw8 = *(const bf16x8*)(pW + (size_t)(wave * 4 + kt) * 512 + lane * 8);
    bf16x8 bg8 = *(const bf16x8*)(pG + (size_t)(wave * 4 + kt) * 512 + lane * 8);
    aW[0] = mfma16(ah0, bw8, aW[0]);
    aW[1] = mfma16(ah1, bw8, aW[1]);
    aG[0] = mfma16(ag0, bg8, aG[0]);
    aG[1] = mfma16(ag1, bg8, aG[1]);
  }
}

__device__ __forceinline__ void run_chain(
    const short* xsb, short* hsb, short* gsb,
    const short* __restrict__ pW0, const short* __restrict__ pG0,
    const short* __restrict__ pW1, const short* __restrict__ pG1,
    const short* __restrict__ pW2, const short* __restrict__ pG2,
    const float* __restrict__ B0, const float* __restrict__ Gb0,
    const float* __restrict__ B1, const float* __restrict__ Gb1,
    const float* __restrict__ B2, const float* __restrict__ Gb2,
    int wave, int lane, f32x4 (&aW)[2], f32x4 (&aG)[2]) {
  const int lrow = lane & 15, lk = lane >> 4;
  const int s0 = (lrow >> 2) & 3;
  {
    float bw = B0[wave * 16 + lrow], bg = Gb0[wave * 16 + lrow];
    aW[0] = {bw, bw, bw, bw}; aW[1] = aW[0];
    aG[0] = {bg, bg, bg, bg}; aG[1] = aG[0];
  }
#pragma unroll
  for (int kt = 0; kt < 12; ++kt) {
    int al = kt * 32 + lk * 8;
    int aoff = (al < 256) ? al : (256 + ((al - 256) ^ (s0 << 4)));  // ef region swizzled
    bf16x8 a0 = *(const bf16x8*)(xsb + (size_t)lrow * XSS + aoff);
    bf16x8 a1 = *(const bf16x8*)(xsb + (size_t)(16 + lrow) * XSS + aoff);
    bf16x8 bw8 = *(const bf16x8*)(pW0 + (size_t)(wave * 12 + kt) * 512 + lane * 8);
    bf16x8 bg8 = *(const bf16x8*)(pG0 + (size_t)(wave * 12 + kt) * 512 + lane * 8);
    aW[0] = mfma16(a0, bw8, aW[0]);
    aW[1] = mfma16(a1, bw8, aW[1]);
    aG[0] = mfma16(a0, bg8, aG[0]);
    aG[1] = mfma16(a1, bg8, aG[1]);
  }
  store_hg(hsb, gsb, wave, lane, aW, aG);
  __syncthreads();
  layer128w(hsb, gsb, pW1, pG1, B1, Gb1, wave, lane, aW, aG);
  __syncthreads();
  store_hg(hsb, gsb, wave, lane, aW, aG);
  __syncthreads();
  layer128w(hsb, gsb, pW2, pG2, B2, Gb2, wave, lane, aW, aG);
}

template <int ISK0>
__global__ __launch_bounds__(512, 6) void gmlp_fused(
    const float* __restrict__ nf, float* __restrict__ ef, const float* __restrict__ rbf,
    const int* __restrict__ src, const int* __restrict__ dst,
    const ushort* __restrict__ stbp, const int* __restrict__ sa,
    const int* __restrict__ off_e, const int* __restrict__ cnt_e,
    const float* __restrict__ atoms, const int* __restrict__ invp,
    const short* __restrict__ ptbW, const short* __restrict__ ptbG,
    const short* __restrict__ peW, const float* __restrict__ eB,
    const short* __restrict__ pW0a, const short* __restrict__ pG0a,
    const short* __restrict__ pW1a, const short* __restrict__ pG1a,
    const short* __restrict__ pW2a, const short* __restrict__ pG2a,
    const float* __restrict__ B0a, const float* __restrict__ Gb0a,
    const float* __restrict__ B1a, const float* __restrict__ Gb1a,
    const float* __restrict__ B2a, const float* __restrict__ Gb2a,
    const short* __restrict__ pWTa,
    const short* __restrict__ pW0b, const short* __restrict__ pG0b,
    const short* __restrict__ pW1b, const short* __restrict__ pG1b,
    const short* __restrict__ pW2b, const short* __restrict__ pG2b,
    const float* __restrict__ B0b, const float* __restrict__ Gb0b,
    const float* __restrict__ B1b, const float* __restrict__ Gb1b,
    const float* __restrict__ B2b, const float* __restrict__ Gb2b,
    const short* __restrict__ pWTb,
    float* __restrict__ mbuf, int E, int writeEf) {
  __shared__ __align__(16) short xs[32][XSS];
  __shared__ __align__(16) short hs[32 * HSS];
  __shared__ __align__(16) short gs[32 * HSS];
  __shared__ __align__(16) short nbl[32][40];  // K=32-padded nb, bf16
  __shared__ __align__(16) short rbl[32][40];  // K=32-padded rbf, bf16
  __shared__ int invs[32];
  const int tid = threadIdx.x;
  const int e0 = blockIdx.x * TE;
  const int r = tid >> 4, q = tid & 15;
  int eg = e0 + r; if (eg >= E) eg = E - 1;

  // ---- fused nb_reduce -> bf16 nbl (zero-pad K 9..31) ----
  {
    float acc = 0.f;
    if (q < 9) {
      int o = off_e[eg], c = cnt_e[eg];
      for (int pp = o; pp < o + c; ++pp)
        acc += bf2f(stbp[(size_t)pp * 9 + q]) * atoms[(size_t)sa[pp] * 9 + q];
    }
    nbl[r][q] = (q < 9) ? f2bf1(acc) : (short)0;
    nbl[r][q + 16] = 0;
  }
  // ---- gather nf segments as bf16; rbf -> rbl bf16 ----
  {
    const float* sp0 = nf + (size_t)src[eg] * 128;
    const float* sp1 = nf + (size_t)dst[eg] * 128;
#pragma unroll
    for (int seg = 0; seg < 2; ++seg) {
      const float* sp = seg == 0 ? sp0 : sp1;
      float4 f0 = *(const float4*)(sp + q * 8);
      float4 f1 = *(const float4*)(sp + q * 8 + 4);
      u32x4 v = {cvt2(f0.x, f0.y), cvt2(f0.z, f0.w), cvt2(f1.x, f1.y), cvt2(f1.z, f1.w)};
      *(u32x4*)&xs[r][seg * 128 + q * 8] = v;
    }
    for (int idx = tid; idx < 32 * 32; idx += 512) {
      int rr = idx >> 5, d = idx & 31;
      int ee = e0 + rr; if (ee >= E) ee = E - 1;
      rbl[rr][d] = (d < 9) ? f2bf1(rbf[ee * 9 + d]) : (short)0;
    }
    if (tid < 32) {
      int ee = e0 + tid; if (ee >= E) ee = E - 1;
      invs[tid] = invp[ee];
    }
  }
  __syncthreads();

  const int wave = tid >> 6;
  const int lane = tid & 63;
  const int lrow = lane & 15, lk = lane >> 4;
  const int col = wave * 16 + lrow;
  const int cs = 256 + (col ^ (lk << 4));
  f32x4 aW[2], aG[2];
  float efb[2][4];  // ef + tb_update base, carried in registers through chain 0

  // ---- tb_update via MFMA (+ compile-time edge_emb fusion at k=0) ----
  {
    bf16x8 ta0 = *(const bf16x8*)&nbl[lrow][lk * 8];
    bf16x8 ta1 = *(const bf16x8*)&nbl[16 + lrow][lk * 8];
    bf16x8 tbw = *(const bf16x8*)(ptbW + wave * 512 + lane * 8);
    bf16x8 tbg = *(const bf16x8*)(ptbG + wave * 512 + lane * 8);
    f32x4 z = {0.f, 0.f, 0.f, 0.f};
    f32x4 tW0 = mfma16(ta0, tbw, z), tW1 = mfma16(ta1, tbw, z);
    f32x4 tG0 = mfma16(ta0, tbg, z), tG1 = mfma16(ta1, tbg, z);
    if (ISK0) {  // ef = silu(rbf @ eW + eB), computed in-place
      bf16x8 ra0 = *(const bf16x8*)&rbl[lrow][lk * 8];
      bf16x8 ra1 = *(const bf16x8*)&rbl[16 + lrow][lk * 8];
      bf16x8 ew8 = *(const bf16x8*)(peW + wave * 512 + lane * 8);
      float ebv = eB[col];
      f32x4 ec = {ebv, ebv, ebv, ebv};
      f32x4 e0v = mfma16(ra0, ew8, ec);
      f32x4 e1v = mfma16(ra1, ew8, ec);
#pragma unroll
      for (int mt = 0; mt < 2; ++mt)
#pragma unroll
        for (int rg = 0; rg < 4; ++rg) {
          int row = mt * 16 + lk * 4 + rg;
          float tw = mt == 0 ? tW0[rg] : tW1[rg];
          float tg = mt == 0 ? tG0[rg] : tG1[rg];
          float base = silu(mt == 0 ? e0v[rg] : e1v[rg]) + tw * sig2(tw, tg);
          efb[mt][rg] = base;
          xs[row][cs] = f2bf1(base);
        }
    } else {
#pragma unroll
      for (int mt = 0; mt < 2; ++mt)
#pragma unroll
        for (int rg = 0; rg < 4; ++rg) {
          int row = mt * 16 + lk * 4 + rg;
          int ec2 = e0 + row; if (ec2 >= E) ec2 = E - 1;
          float tw = mt == 0 ? tW0[rg] : tW1[rg];
          float tg = mt == 0 ? tG0[rg] : tG1[rg];
          float base = ef[(size_t)ec2 * 128 + col] + tw * sig2(tw, tg);
          efb[mt][rg] = base;
          xs[row][cs] = f2bf1(base);
        }
    }
  }
  __syncthreads();

  // ---- chain 0: edge update ----
  run_chain(&xs[0][0], hs, gs, pW0a, pG0a, pW1a, pG1a, pW2a, pG2a,
            B0a, Gb0a, B1a, Gb1a, B2a, Gb2a, wave, lane, aW, aG);
  {
    bf16x8 ra0 = *(const bf16x8*)&rbl[lrow][lk * 8];
    bf16x8 ra1 = *(const bf16x8*)&rbl[16 + lrow][lk * 8];
    bf16x8 wtb = *(const bf16x8*)(pWTa + wave * 512 + lane * 8);
    f32x4 z = {0.f, 0.f, 0.f, 0.f};
    f32x4 wv0 = mfma16(ra0, wtb, z), wv1 = mfma16(ra1, wtb, z);
#pragma unroll
    for (int mt = 0; mt < 2; ++mt)
#pragma unroll
      for (int rg = 0; rg < 4; ++rg) {
        int row = mt * 16 + lk * 4 + rg;
        int e = e0 + row;
        float wv = mt == 0 ? wv0[rg] : wv1[rg];
        float a = aW[mt][rg], g = aG[mt][rg];
        float v = a * sig2(a, g) * wv;
        float nv = efb[mt][rg] + v;
        if (e < E && writeEf) ef[(size_t)e * 128 + col] = nv;
        xs[row][cs] = f2bf1(nv);
      }
  }
  __syncthreads();

  // ---- chain 1: node update ----
  run_chain(&xs[0][0], hs, gs, pW0b, pG0b, pW1b, pG1b, pW2b, pG2b,
            B0b, Gb0b, B1b, Gb1b, B2b, Gb2b, wave, lane, aW, aG);
  {
    bf16x8 ra0 = *(const bf16x8*)&rbl[lrow][lk * 8];
    bf16x8 ra1 = *(const bf16x8*)&rbl[16 + lrow][lk * 8];
    bf16x8 wtb = *(const bf16x8*)(pWTb + wave * 512 + lane * 8);
    f32x4 z = {0.f, 0.f, 0.f, 0.f};
    f32x4 wv0 = mfma16(ra0, wtb, z), wv1 = mfma16(ra1, wtb, z);
#pragma unroll
    for (int mt = 0; mt < 2; ++mt)
#pragma unroll
      for (int rg = 0; rg < 4; ++rg) {
        int row = mt * 16 + lk * 4 + rg;
        int e = e0 + row;
        float wv = mt == 0 ? wv0[rg] : wv1[rg];
        float a = aW[mt][rg], g = aG[mt][rg];
        float v = a * sig2(a, g) * wv;
        if (e < E) mbuf[(size_t)invs[row] * 128 + col] = v;  // dst-sorted position
      }
  }
}

// ---- node gather (sequential, dst-sorted mbuf) + parallel fused atoms ----
__global__ void node_gather_kernel(float* __restrict__ nf, const float* __restrict__ mbuf,
                                   const int* __restrict__ off_n, const int* __restrict__ cnt_n,
                                   const float* __restrict__ taW, const float* __restrict__ taB,
                                   float* __restrict__ atoms, int N, int doAtoms) {
  __shared__ float red[2][9][128];
  int half = threadIdx.x >> 7, c = threadIdx.x & 127;
  int n = blockIdx.x * 2 + half;
  float v = 0.f;
  if (n < N) {
    int o = off_n[n], cnt = cnt_n[n];
    float acc = 0.f;
    for (int p = 0; p < cnt; ++p) acc += mbuf[(size_t)(o + p) * 128 + c];
    v = nf[(size_t)n * 128 + c] + acc;
    nf[(size_t)n * 128 + c] = v;
  }
  if (doAtoms) {
#pragma unroll
    for (int d = 0; d < 9; ++d) red[half][d][c] = (n < N) ? v * taW[c * 9 + d] : 0.f;
    for (int s = 64; s >= 1; s >>= 1) {
      __syncthreads();
      for (int idx = threadIdx.x; idx < 2 * 9 * s; idx += 256) {
        int h = idx / (9 * s), rem = idx - h * 9 * s;
        int d = rem / s, j = rem - d * s;
        red[h][d][j] += red[h][d][j + s];
      }
    }
    __syncthreads();
    if (threadIdx.x < 18) {
      int h = threadIdx.x / 9, d = threadIdx.x - h * 9;
      int nn = blockIdx.x * 2 + h;
      if (nn < N) atoms[nn * 9 + d] = sigm(red[h][d][0] + taB[d]);
    }
  }
}

// ---------------- readout ----------------
__global__ void mean_kernel(const float* __restrict__ nf, float* __restrict__ partial, int N) {
  __shared__ float sm[256];
  int n0 = blockIdx.x * 256;
  int col = threadIdx.x & 127, half = threadIdx.x >> 7;
  int nend = n0 + 256 < N ? n0 + 256 : N;
  float s = 0.f;
  for (int n = n0 + half; n < nend; n += 2) s += nf[n * 128 + col];
  sm[threadIdx.x] = s;
  __syncthreads();
  if (threadIdx.x < 128)
    partial[blockIdx.x * 128 + threadIdx.x] = sm[threadIdx.x] + sm[threadIdx.x + 128];
}

__global__ void final_kernel(const float* __restrict__ partial, int nchunks, float Nf,
                             const float* __restrict__ fW0, const float* __restrict__ fb0,
                             const float* __restrict__ fW1, const float* __restrict__ fb1,
                             const float* __restrict__ fW2, const float* __restrict__ fb2,
                             float* __restrict__ out) {
  __shared__ float v[128], h[128], red[128];
  int tid = threadIdx.x;  // 128 threads
  float s = 0.f;
  for (int b = 0; b < nchunks; ++b) s += partial[b * 128 + tid];
  v[tid] = s / Nf;
  __syncthreads();
  float acc = fb0[tid];
  for (int c = 0; c < 128; ++c) acc += v[c] * fW0[c * 128 + tid];
  h[tid] = silu(acc);
  __syncthreads();
  acc = fb1[tid];
  for (int c = 0; c < 128; ++c) acc += h[c] * fW1[c * 128 + tid];
  __syncthreads();
  v[tid] = silu(acc);
  __syncthreads();
  red[tid] = v[tid] * fW2[tid];
  __syncthreads();
  for (int st = 64; st > 0; st >>= 1) {
    if (tid < st) red[tid] += red[tid + st];
    __syncthreads();
  }
  if (tid == 0) out[0] = red[0] + fb2[0];
}

// ---------------- launch ----------------
extern "C" void kernel_launch(void* const* d_in, const int* in_sizes, int n_in,
                              void* d_out, int out_size, void* d_ws, size_t ws_size,
                              hipStream_t stream) {
  const float* pos = (const float*)d_in[0];
  const int* node_type = (const int*)d_in[1];
  const int* src = (const int*)d_in[2];
  const int* dst = (const int*)d_in[3];
  const int* t_src = (const int*)d_in[4];
  const int* t_dst = (const int*)d_in[5];
  const float* emb = (const float*)d_in[6];
  const float* eW = (const float*)d_in[7];
  const float* eB = (const float*)d_in[8];
  const float* taW = (const float*)d_in[9];
  const float* taB = (const float*)d_in[10];
  const float* tbW = (const float*)d_in[11];
  const float* tbG = (const float*)d_in[12];
  const float* W0 = (const float*)d_in[13]; const float* B0 = (const float*)d_in[14];
  const float* W1 = (const float*)d_in[15]; const float* B1 = (const float*)d_in[16];
  const float* W2 = (const float*)d_in[17]; const float* B2 = (const float*)d_in[18];
  const float* G0 = (const float*)d_in[19]; const float* Gb0 = (const float*)d_in[20];
  const float* G1 = (const float*)d_in[21]; const float* Gb1 = (const float*)d_in[22];
  const float* G2 = (const float*)d_in[23]; const float* Gb2 = (const float*)d_in[24];
  const float* WT = (const float*)d_in[25];
  const float* fW0 = (const float*)d_in[26]; const float* fb0 = (const float*)d_in[27];
  const float* fW1 = (const float*)d_in[28]; const float* fb1 = (const float*)d_in[29];
  const float* fW2 = (const float*)d_in[30]; const float* fb2 = (const float*)d_in[31];

  const int N = in_sizes[1];
  const int E = in_sizes[2];
  const int T = in_sizes[4];

  char* p = (char*)d_ws;
  auto alloc = [&](size_t bytes) -> char* {
    char* r = p;
    p += (bytes + 255) & ~(size_t)255;
    return r;
  };
  float*  nf    = (float*)alloc((size_t)N * 128 * 4);
  float*  ef    = (float*)alloc((size_t)E * 128 * 4);
  float*  mbuf  = (float*)alloc((size_t)E * 128 * 4);
  float*  rbf   = (float*)alloc((size_t)E * 9 * 4);
  float*  bvec  = (float*)alloc((size_t)E * 3 * 4);
  float*  bdist = (float*)alloc((size_t)E * 4);
  float*  cut3  = (float*)alloc((size_t)E * 4);
  ushort* stbp  = (ushort*)alloc((size_t)T * 9 * 2);
  int*    sa    = (int*)alloc((size_t)T * 4);
  float*  atoms = (float*)alloc((size_t)N * 9 * 4);
  float*  part  = (float*)alloc((size_t)64 * 128 * 4);
  int* cnt_all = (int*)alloc((size_t)(E + N) * 4);
  int* cnt_e = cnt_all, *cnt_n = cnt_all + E;
  int* incl_e = (int*)alloc((size_t)E * 4);
  int* incl_n = (int*)alloc((size_t)N * 4);
  int* off_e  = (int*)alloc((size_t)E * 4);
  int* off_n  = (int*)alloc((size_t)N * 4);
  int* cur_e  = (int*)alloc((size_t)E * 4);
  int* cur_n  = (int*)alloc((size_t)N * 4);
  int* invp   = (int*)alloc((size_t)E * 4);
  int* bsum_e = (int*)alloc((size_t)1024 * 4);
  int* bsum_n = (int*)alloc((size_t)1024 * 4);
  short* pW0s = (short*)alloc((size_t)6 * 384 * 128 * 2);
  short* pG0s = (short*)alloc((size_t)6 * 384 * 128 * 2);
  short* pW1s = (short*)alloc((size_t)6 * 128 * 128 * 2);
  short* pG1s = (short*)alloc((size_t)6 * 128 * 128 * 2);
  short* pW2s = (short*)alloc((size_t)6 * 128 * 128 * 2);
  short* pG2s = (short*)alloc((size_t)6 * 128 * 128 * 2);
  short* ptbWs = (short*)alloc((size_t)3 * 4096 * 2);
  short* ptbGs = (short*)alloc((size_t)3 * 4096 * 2);
  short* pWTs  = (short*)alloc((size_t)6 * 4096 * 2);
  short* peWs  = (short*)alloc((size_t)4096 * 2);
  (void)ws_size; (void)n_in; (void)out_size;

  const int ebk = (E + 255) / 256, nbk = (N + 255) / 256;

  pack_all_kernel<<<506, 256, 0, stream>>>(W0, G0, W1, G1, W2, G2, tbW, tbG, WT, eW,
                                           pW0s, pG0s, pW1s, pG1s, pW2s, pG2s,
                                           ptbWs, ptbGs, pWTs, peWs, cnt_all, E + N);
  {
    int g1 = N * 128; if (E > g1) g1 = E; if (T > g1) g1 = T;
    setup1_kernel<<<(g1 + 255) / 256, 256, 0, stream>>>(
        node_type, emb, nf, N, pos, src, dst, bvec, bdist, rbf, cut3, E, t_src, cnt_e, cnt_n, T);
  }
  {
    int g2 = (N + 1) / 2; if (ebk + nbk > g2) g2 = ebk + nbk;
    setup2_kernel<<<g2, 256, 0, stream>>>(
        cnt_e, incl_e, bsum_e, ebk, E, cnt_n, incl_n, bsum_n, nbk, N, nf, taW, taB, atoms);
  }
  fin2_kernel<<<ebk + nbk, 256, 0, stream>>>(cnt_e, incl_e, bsum_e, ebk, off_e, cur_e, E,
                                             cnt_n, incl_n, bsum_n, off_n, cur_n, N);
  {
    int g3 = T > E ? T : E;
    build_kernel<<<(g3 + 255) / 256, 256, 0, stream>>>(t_src, t_dst, dst, bvec, bdist, rbf,
                                                       cut3, cur_e, stbp, sa, T, cur_n, invp, E);
  }

  const int gblocks = (E + TE - 1) / TE;
  for (int k = 0; k < 3; ++k) {
    size_t u0 = (size_t)(k * 2 + 0), u1 = u0 + 1;
#define GMLP_ARGS                                                                          \
    nf, ef, rbf, src, dst, stbp, sa, off_e, cnt_e, atoms, invp,                            \
    ptbWs + (size_t)k * 4096, ptbGs + (size_t)k * 4096, peWs, eB,                          \
    pW0s + u0 * 384 * 128, pG0s + u0 * 384 * 128, pW1s + u0 * 128 * 128,                   \
    pG1s + u0 * 128 * 128, pW2s + u0 * 128 * 128, pG2s + u0 * 128 * 128,                   \
    B0 + u0 * 128, Gb0 + u0 * 128, B1 + u0 * 128, Gb1 + u0 * 128, B2 + u0 * 128,           \
    Gb2 + u0 * 128, pWTs + u0 * 4096,                                                      \
    pW0s + u1 * 384 * 128, pG0s + u1 * 384 * 128, pW1s + u1 * 128 * 128,                   \
    pG1s + u1 * 128 * 128, pW2s + u1 * 128 * 128, pG2s + u1 * 128 * 128,                   \
    B0 + u1 * 128, Gb0 + u1 * 128, B1 + u1 * 128, Gb1 + u1 * 128, B2 + u1 * 128,           \
    Gb2 + u1 * 128, pWTs + u1 * 4096,                                                      \
    mbuf, E, k < 2 ? 1 : 0
    if (k == 0) gmlp_fused<1><<<gblocks, 512, 0, stream>>>(GMLP_ARGS);
    else        gmlp_fused<0><<<gblocks, 512, 0, stream>>>(GMLP_ARGS);
#undef GMLP_ARGS
    int nk = k < 2 ? k + 1 : 0;
    node_gather_kernel<<<(N + 1) / 2, 256, 0, stream>>>(
        nf, mbuf, off_n, cnt_n, taW + (size_t)nk * 128 * 9, taB + (size_t)nk * 9,
        atoms, N, k < 2 ? 1 : 0);
  }

  int nchunks = (N + 255) / 256;
  mean_kernel<<<nchunks, 256, 0, stream>>>(nf, part, N);
  final_kernel<<<1, 128, 0, stream>>>(part, nchunks, (float)N, fW0, fb0, fW1, fb1, fW2, fb2,
                                      (float*)d_out);
}